// Round 1
// baseline (391.025 us; speedup 1.0000x reference)
//
#include <hip/hip_runtime.h>
#include <stdint.h>

// VQ-VAE quantize forward, MI355X. Split-f16 MFMA distance GEMM.
// R6: barrier-free main loop. A tile (64 rows) staged+split ONCE into LDS
// (hi/lo f16, chunk^row XOR swizzle, 64KB); B fragments loaded register-
// direct from L2-resident Eh/El (1MB) with a 1-step register double-buffer.
// No __syncthreads between prologue and argmin-merge. 2 blocks/CU
// (LDS ~71KB), 2 waves/SIMD, __launch_bounds__(256,2) -> <=256 VGPR.
// Accumulation order (ah*bh, al*bh, ah*bl per kc) identical to R5 ->
// bit-identical distances/argmin.
// out = [values (BT*D)] [indexes as float (BT)] [loss (1)]

#define BT   65536      // 16*4096 rows
#define D    256        // codeword size
#define KCB  1024       // codebook size
#define BM   64         // rows per block tile
#define NT   8          // col tiles: 8 x (4 waves x 32 cols) = 1024

typedef float    f32x4 __attribute__((ext_vector_type(4)));
typedef _Float16 f16x8 __attribute__((ext_vector_type(8)));

// ---- split E -> Eh, El + fp32 |e|^2 (1MB input; ~3us) ----
__global__ __launch_bounds__(256) void split_e_kernel(const float* __restrict__ E,
                                                      _Float16* __restrict__ Eh,
                                                      _Float16* __restrict__ El,
                                                      float* __restrict__ enorm) {
    const int r = blockIdx.x * 8 + (threadIdx.x >> 5);
    const size_t i0 = (size_t)r * D + (threadIdx.x & 31) * 8;
    float4 v0 = *(const float4*)(E + i0);
    float4 v1 = *(const float4*)(E + i0 + 4);
    float v[8] = {v0.x, v0.y, v0.z, v0.w, v1.x, v1.y, v1.z, v1.w};
    f16x8 h, l;
    float s = 0.f;
    #pragma unroll
    for (int j = 0; j < 8; ++j) {
        _Float16 hh = (_Float16)v[j];
        h[j] = hh;
        l[j] = (_Float16)(v[j] - (float)hh);
        s += v[j] * v[j];
    }
    *(f16x8*)(Eh + i0) = h;
    *(f16x8*)(El + i0) = l;
    #pragma unroll
    for (int off = 1; off < 32; off <<= 1) s += __shfl_xor(s, off, 64);
    if ((threadIdx.x & 31) == 0) enorm[r] = s;
}

// ---- main: A-persistent barrier-free split-f16 MFMA + argmin + gather + loss
__global__ __launch_bounds__(256, 2) void vq_mfma_kernel(
    const float* __restrict__ X, const float* __restrict__ E,
    const _Float16* __restrict__ Eh, const _Float16* __restrict__ El,
    const float* __restrict__ enorm,
    float* __restrict__ out_vals, float* __restrict__ out_idx,
    float* __restrict__ out_loss) {
    // A rows are 256 f16 = 32 x 16B chunks; physical chunk p = c ^ (r&7)
    // (same family as R3-verified swizzle; read pattern is 2-way -> free).
    __shared__ __align__(16) _Float16 Ah[BM * D];   // 32 KB
    __shared__ __align__(16) _Float16 Al[BM * D];   // 32 KB
    __shared__ float s_en[KCB];                     // 4 KB
    __shared__ float s_wd[4 * BM];                  // 1 KB
    __shared__ int   s_wi[4 * BM];                  // 1 KB
    __shared__ int   s_fi[BM];
    __shared__ float s_red[4];

    const int tid  = threadIdx.x;
    const int w    = tid >> 6;        // wave 0..3 -> col slice w*32
    const int lane = tid & 63;
    const int quad = lane >> 4;
    const int l16  = lane & 15;
    const int swz  = l16 & 7;         // row&7 for frag reads (i*16 == 0 mod 8)
    const int row0 = blockIdx.x * BM;

    // ---- prologue: X tile -> registers -> split hi/lo -> swizzled LDS ----
    {
        const int pr = tid >> 5;          // 0..7
        const int kk = (tid & 31) * 8;    // 0..248
        const int c  = kk >> 3;           // logical chunk 0..31
        #pragma unroll
        for (int pass = 0; pass < 8; ++pass) {
            const int r = pass * 8 + pr;
            const float* xp = X + (size_t)(row0 + r) * D + kk;
            const float4 v0 = *(const float4*)xp;
            const float4 v1 = *(const float4*)(xp + 4);
            const float v[8] = {v0.x, v0.y, v0.z, v0.w, v1.x, v1.y, v1.z, v1.w};
            f16x8 h, l;
            #pragma unroll
            for (int e = 0; e < 8; ++e) {
                const _Float16 hh = (_Float16)v[e];
                h[e] = hh;
                l[e] = (_Float16)(v[e] - (float)hh);
            }
            const int p = c ^ (r & 7);
            *(f16x8*)&Ah[r * D + p * 8] = h;
            *(f16x8*)&Al[r * D + p * 8] = l;
        }
        for (int t = tid; t < KCB; t += 256) s_en[t] = enorm[t];
    }
    __syncthreads();   // last barrier before the merge phase

    float rb_d[4][4];
    int   rb_i[4][4];
    #pragma unroll
    for (int i = 0; i < 4; ++i)
        #pragma unroll
        for (int r = 0; r < 4; ++r) { rb_d[i][r] = 3.4e38f; rb_i[i][r] = 0; }

    // B fragment base: col = nt*128 + w*32 + j*16 + l16, k = kc*32 + quad*8
    const _Float16* __restrict__ bh_base = Eh + (size_t)(w * 32 + l16) * D + quad * 8;
    const _Float16* __restrict__ bl_base = El + (size_t)(w * 32 + l16) * D + quad * 8;
    #define BOFF(nt_, kc_) ((nt_) * 128 * D + (kc_) * 32)

    f16x8 cbh0 = *(const f16x8*)(bh_base + BOFF(0, 0));
    f16x8 cbh1 = *(const f16x8*)(bh_base + BOFF(0, 0) + 16 * D);
    f16x8 cbl0 = *(const f16x8*)(bl_base + BOFF(0, 0));
    f16x8 cbl1 = *(const f16x8*)(bl_base + BOFF(0, 0) + 16 * D);

    for (int nt = 0; nt < NT; ++nt) {
        f32x4 acc[4][2];
        #pragma unroll
        for (int i = 0; i < 4; ++i) { acc[i][0] = (f32x4)0.0f; acc[i][1] = (f32x4)0.0f; }

        #pragma unroll
        for (int kc = 0; kc < 8; ++kc) {
            // prefetch next step's B frags (wraps harmlessly at the very end)
            const int sn  = (nt * 8 + kc + 1) & 63;
            const int nof = BOFF(sn >> 3, sn & 7);
            f16x8 nbh0 = *(const f16x8*)(bh_base + nof);
            f16x8 nbh1 = *(const f16x8*)(bh_base + nof + 16 * D);
            f16x8 nbl0 = *(const f16x8*)(bl_base + nof);
            f16x8 nbl1 = *(const f16x8*)(bl_base + nof + 16 * D);

            const int ko = ((kc * 4 + quad) ^ swz) << 3;   // swizzled 16B chunk
            const int ab = l16 * D + ko;
            #pragma unroll
            for (int i = 0; i < 4; ++i) {
                const int ai = ab + i * 16 * D;
                const f16x8 ah = *(const f16x8*)&Ah[ai];
                const f16x8 al = *(const f16x8*)&Al[ai];
                acc[i][0] = __builtin_amdgcn_mfma_f32_16x16x32_f16(ah, cbh0, acc[i][0], 0, 0, 0);
                acc[i][1] = __builtin_amdgcn_mfma_f32_16x16x32_f16(ah, cbh1, acc[i][1], 0, 0, 0);
                acc[i][0] = __builtin_amdgcn_mfma_f32_16x16x32_f16(al, cbh0, acc[i][0], 0, 0, 0);
                acc[i][1] = __builtin_amdgcn_mfma_f32_16x16x32_f16(al, cbh1, acc[i][1], 0, 0, 0);
                acc[i][0] = __builtin_amdgcn_mfma_f32_16x16x32_f16(ah, cbl0, acc[i][0], 0, 0, 0);
                acc[i][1] = __builtin_amdgcn_mfma_f32_16x16x32_f16(ah, cbl1, acc[i][1], 0, 0, 0);
            }
            cbh0 = nbh0; cbh1 = nbh1; cbl0 = nbl0; cbl1 = nbl1;
        }

        // score = |e|^2 - 2 x.e ; cols ascend (j then nt) -> strict <
        #pragma unroll
        for (int j = 0; j < 2; ++j) {
            const int c = nt * 128 + w * 32 + j * 16 + l16;
            const float en = s_en[c];
            #pragma unroll
            for (int i = 0; i < 4; ++i)
                #pragma unroll
                for (int r = 0; r < 4; ++r) {
                    const float s = en - 2.0f * acc[i][j][r];
                    if (s < rb_d[i][r]) { rb_d[i][r] = s; rb_i[i][r] = c; }
                }
        }
    }

    // fold the 16 lanes of each quad (they partition this wave's col slice)
    #pragma unroll
    for (int off = 1; off < 16; off <<= 1) {
        #pragma unroll
        for (int i = 0; i < 4; ++i)
            #pragma unroll
            for (int r = 0; r < 4; ++r) {
                const float od = __shfl_xor(rb_d[i][r], off, 64);
                const int   oi = __shfl_xor(rb_i[i][r], off, 64);
                if (od < rb_d[i][r] || (od == rb_d[i][r] && oi < rb_i[i][r])) {
                    rb_d[i][r] = od; rb_i[i][r] = oi;
                }
            }
    }
    // each wave covers all 64 rows (distinct col slices): merge via LDS
    if (l16 == 0) {
        #pragma unroll
        for (int i = 0; i < 4; ++i)
            #pragma unroll
            for (int r = 0; r < 4; ++r) {
                const int m = i * 16 + quad * 4 + r;
                s_wd[w * BM + m] = rb_d[i][r];
                s_wi[w * BM + m] = rb_i[i][r];
            }
    }
    __syncthreads();
    if (tid < BM) {
        float bd = s_wd[tid];
        int   bi = s_wi[tid];
        #pragma unroll
        for (int ww = 1; ww < 4; ++ww) {
            const float od = s_wd[ww * BM + tid];
            const int   oi = s_wi[ww * BM + tid];
            if (od < bd || (od == bd && oi < bi)) { bd = od; bi = oi; }
        }
        s_fi[tid] = bi;
        out_idx[row0 + tid] = (float)bi;
    }
    __syncthreads();

    // epilogue: gather values (straight-through fwd == values); x rebuilt
    // from LDS hi+lo (err ~2^-22 rel, only feeds the loss scalar)
    float lsum = 0.f;
    const int ccol = tid >> 3;          // this thread's logical chunk
    for (int r = 0; r < BM; ++r) {
        const int bi = s_fi[r];
        const float ev = E[(size_t)bi * D + tid];
        out_vals[(size_t)(row0 + r) * D + tid] = ev;
        const int ax = r * D + ((ccol ^ (r & 7)) << 3) + (tid & 7);
        const float xv = (float)Ah[ax] + (float)Al[ax];
        const float dd = xv - ev;
        lsum += dd * dd;
    }

    #pragma unroll
    for (int off = 1; off < 64; off <<= 1) lsum += __shfl_xor(lsum, off, 64);
    if (lane == 0) s_red[w] = lsum;
    __syncthreads();
    if (tid == 0) {
        const float total = s_red[0] + s_red[1] + s_red[2] + s_red[3];
        atomicAdd(out_loss, total * (1.1f / 16777216.f));  // loss1 + 0.1*loss2
    }
}

extern "C" void kernel_launch(void* const* d_in, const int* in_sizes, int n_in,
                              void* d_out, int out_size, void* d_ws, size_t ws_size,
                              hipStream_t stream) {
    const float* X = (const float*)d_in[0];
    const float* E = (const float*)d_in[1];
    float* out      = (float*)d_out;
    float* out_vals = out;
    float* out_idx  = out + (size_t)BT * D;
    float* out_loss = out + (size_t)BT * D + BT;

    char* ws = (char*)d_ws;
    _Float16* Eh = (_Float16*)ws;
    _Float16* El = Eh + (size_t)KCB * D;
    float*    enorm = (float*)(El + (size_t)KCB * D);
    (void)ws_size; (void)n_in; (void)in_sizes; (void)out_size;

    hipMemsetAsync(out_loss, 0, sizeof(float), stream);  // d_out poisoned 0xAA
    split_e_kernel<<<KCB / 8, 256, 0, stream>>>(E, Eh, El, enorm);
    vq_mfma_kernel<<<BT / BM, 256, 0, stream>>>(X, E, Eh, El, enorm,
                                                out_vals, out_idx, out_loss);
}

// Round 2
// 244.115 us; speedup vs baseline: 1.6018x; 1.6018x over previous
//
#include <hip/hip_runtime.h>
#include <stdint.h>

// VQ-VAE quantize forward, MI355X. Split-f16 MFMA distance GEMM.
// R7: counted-vmcnt double-buffered pipeline (T3+T4), raw s_barrier, never
// vmcnt(0) in the loop. BM=256 x BN=128 x BK=32, 512 thr (8 waves, 4Mx2N),
// grid=256 = 1 block/CU exactly. A fp32 via global_load_lds (R5-verified
// c^(r&7) swizzle), split hi/lo in-register after ds_read; B hi/lo f16 via
// global_load_lds (R5-verified (c+(r>>1))&3 swizzle). 6 loads/thread/step
// -> s_waitcnt vmcnt(6) steady state. setprio around MFMA cluster (T5).
// Loss = sum|x|^2 + sum(min dist) -> no epilogue X re-read.
// Distances bit-identical to R5 (same split math, same MFMA order).
// out = [values (BT*D)] [indexes as float (BT)] [loss (1)]

#define BT    65536     // 16*4096 rows
#define D     256       // codeword size
#define KCB   1024      // codebook size
#define BM    256       // rows per block tile
#define BN    128       // cols per n-tile
#define NT    (KCB/BN)  // 8 col tiles
#define BK    32        // k chunk
#define NSTEP (NT * (D / BK))   // 64 pipelined steps

typedef float    f32x4 __attribute__((ext_vector_type(4)));
typedef _Float16 f16x8 __attribute__((ext_vector_type(8)));

#define GLOAD_LDS16(g, l) \
  __builtin_amdgcn_global_load_lds((const __attribute__((address_space(1))) void*)(g), \
                                   (__attribute__((address_space(3))) void*)(l), 16, 0, 0)

// ---- split E -> Eh, El + fp32 |e|^2 (1MB input; ~3us) ----
__global__ __launch_bounds__(256) void split_e_kernel(const float* __restrict__ E,
                                                      _Float16* __restrict__ Eh,
                                                      _Float16* __restrict__ El,
                                                      float* __restrict__ enorm) {
    const int r = blockIdx.x * 8 + (threadIdx.x >> 5);
    const size_t i0 = (size_t)r * D + (threadIdx.x & 31) * 8;
    float4 v0 = *(const float4*)(E + i0);
    float4 v1 = *(const float4*)(E + i0 + 4);
    float v[8] = {v0.x, v0.y, v0.z, v0.w, v1.x, v1.y, v1.z, v1.w};
    f16x8 h, l;
    float s = 0.f;
    #pragma unroll
    for (int j = 0; j < 8; ++j) {
        _Float16 hh = (_Float16)v[j];
        h[j] = hh;
        l[j] = (_Float16)(v[j] - (float)hh);
        s += v[j] * v[j];
    }
    *(f16x8*)(Eh + i0) = h;
    *(f16x8*)(El + i0) = l;
    #pragma unroll
    for (int off = 1; off < 32; off <<= 1) s += __shfl_xor(s, off, 64);
    if ((threadIdx.x & 31) == 0) enorm[r] = s;
}

// ---- main: pipelined split-f16 MFMA + argmin + gather + loss ----
__global__ __launch_bounds__(512, 2) void vq_mfma_kernel(
    const float* __restrict__ X, const float* __restrict__ E,
    const _Float16* __restrict__ Eh, const _Float16* __restrict__ El,
    const float* __restrict__ enorm,
    float* __restrict__ out_vals, float* __restrict__ out_idx,
    float* __restrict__ out_loss) {
    __shared__ __align__(16) float    Asf[2][BM * BK];   // 2 x 32 KB fp32 A
    __shared__ __align__(16) _Float16 Bsh[2][BN * BK];   // 2 x 8 KB
    __shared__ __align__(16) _Float16 Bsl[2][BN * BK];   // 2 x 8 KB
    __shared__ float s_en[KCB];                          // 4 KB
    __shared__ float s_wd[2 * BM];                       // 2 KB
    __shared__ int   s_wi[2 * BM];                       // 2 KB
    __shared__ float s_red[8];

    const int tid  = threadIdx.x;
    const int w    = tid >> 6;        // wave 0..7
    const int lane = tid & 63;
    const int quad = lane >> 4;
    const int l16  = lane & 15;
    const int wm   = w >> 1;          // wave row group (0..3) -> rows wm*64..+63
    const int wn   = w & 1;           // wave col group (0..1) -> cols wn*64..+63
    const int swz  = l16 & 7;
    const int row0 = blockIdx.x * BM;

    // staging lane constants (linear LDS dest = base + lane*16; swizzle folded
    // into the per-lane GLOBAL source address — both-sides-or-neither rule)
    const int a_r = lane >> 3;                                  // row within 8-row chunk
    const int a_k = (((lane & 7) ^ a_r) << 2);                  // float offset in 32-f row
    const int b_r = lane >> 2;                                  // row within 16-row chunk
    const int b_k = ((((lane & 3) - (lane >> 3)) & 3) << 3);    // f16 offset in 32-h row
    // B frag-read physical slot (col bases are multiples of 16 -> same for all j)
    const int kob = ((quad + ((l16 >> 1) & 3)) & 3) << 3;

    // s_en fill (2 global loads; compiler drains them before the ds_write)
    s_en[tid]       = enorm[tid];
    s_en[tid + 512] = enorm[tid + 512];

    auto STAGE = [&](int buf, int s) {
        const int kb   = (s & 7) * BK;
        const int col0 = (s >> 3) * BN;
        #pragma unroll
        for (int t = 0; t < 4; ++t) {
            const int chunk = w * 4 + t;                 // 0..31 (8 rows each)
            const int gr = row0 + chunk * 8 + a_r;
            GLOAD_LDS16(X + (size_t)gr * D + kb + a_k, &Asf[buf][chunk * 256]);
        }
        {
            const int gr = col0 + w * 16 + b_r;          // chunk w: 16 rows
            const size_t gb = (size_t)gr * D + kb + b_k;
            GLOAD_LDS16(Eh + gb, &Bsh[buf][w * 512]);
            GLOAD_LDS16(El + gb, &Bsl[buf][w * 512]);
        }
    };  // 6 loads per thread per call

    float rb_d[4][4];
    int   rb_i[4][4];
    #pragma unroll
    for (int i = 0; i < 4; ++i)
        #pragma unroll
        for (int r = 0; r < 4; ++r) { rb_d[i][r] = 3.4e38f; rb_i[i][r] = 0; }
    float xs = 0.f;               // sum of x^2 (accumulated once, nt==0, wn==0)
    f32x4 acc[4][4];

    STAGE(0, 0);
    asm volatile("s_waitcnt lgkmcnt(0)" ::: "memory");   // s_en writes done

    #pragma unroll 2
    for (int s = 0; s < NSTEP; ++s) {
        const int cur = s & 1;
        if (s + 1 < NSTEP) {
            STAGE(cur ^ 1, s + 1);                       // 6 loads in flight
            asm volatile("s_waitcnt vmcnt(6)" ::: "memory");  // wait only cur's 6
        } else {
            asm volatile("s_waitcnt vmcnt(0)" ::: "memory");
        }
        __builtin_amdgcn_s_barrier();                    // cur fully landed

        if ((s & 7) == 0) {
            #pragma unroll
            for (int i = 0; i < 4; ++i)
                #pragma unroll
                for (int j = 0; j < 4; ++j) acc[i][j] = (f32x4)0.0f;
        }

        const float*    As = Asf[cur];
        const _Float16* Bh = Bsh[cur];
        const _Float16* Bl = Bsl[cur];

        // A frags: read fp32, split to f16 hi/lo in-register
        f16x8 ah[4], al[4];
        #pragma unroll
        for (int i = 0; i < 4; ++i) {
            const float* rp = As + (wm * 64 + i * 16 + l16) * BK;
            const f32x4 v0 = *(const f32x4*)(rp + ((((quad << 1))     ^ swz) << 2));
            const f32x4 v1 = *(const f32x4*)(rp + ((((quad << 1) | 1) ^ swz) << 2));
            const float f[8] = {v0.x, v0.y, v0.z, v0.w, v1.x, v1.y, v1.z, v1.w};
            #pragma unroll
            for (int e = 0; e < 8; ++e) {
                const _Float16 hh = (_Float16)f[e];
                ah[i][e] = hh;
                al[i][e] = (_Float16)(f[e] - (float)hh);
            }
            if (wn == 0 && s < 8) {        // each x element hits exactly once
                #pragma unroll
                for (int e = 0; e < 8; ++e) xs += f[e] * f[e];
            }
        }

        __builtin_amdgcn_s_setprio(1);
        #pragma unroll
        for (int j = 0; j < 4; ++j) {
            const int colr = wn * 64 + j * 16 + l16;
            const f16x8 bh = *(const f16x8*)(Bh + colr * BK + kob);
            const f16x8 bl = *(const f16x8*)(Bl + colr * BK + kob);
            #pragma unroll
            for (int i = 0; i < 4; ++i) {
                acc[i][j] = __builtin_amdgcn_mfma_f32_16x16x32_f16(ah[i], bh, acc[i][j], 0, 0, 0);
                acc[i][j] = __builtin_amdgcn_mfma_f32_16x16x32_f16(al[i], bh, acc[i][j], 0, 0, 0);
                acc[i][j] = __builtin_amdgcn_mfma_f32_16x16x32_f16(ah[i], bl, acc[i][j], 0, 0, 0);
            }
        }
        __builtin_amdgcn_s_setprio(0);

        if ((s & 7) == 7) {                 // nt complete: fold argmin
            const int nt = s >> 3;
            #pragma unroll
            for (int j = 0; j < 4; ++j) {
                const int c = nt * BN + wn * 64 + j * 16 + l16;
                const float en = s_en[c];
                #pragma unroll
                for (int i = 0; i < 4; ++i)
                    #pragma unroll
                    for (int r = 0; r < 4; ++r) {
                        const float sd = en - 2.0f * acc[i][j][r];
                        if (sd < rb_d[i][r]) { rb_d[i][r] = sd; rb_i[i][r] = c; }
                    }
            }
        }
        __builtin_amdgcn_s_barrier();       // all waves done reading cur
    }

    // fold the 16 lanes of each quad (they partition this wave's col slice)
    #pragma unroll
    for (int off = 1; off < 16; off <<= 1) {
        #pragma unroll
        for (int i = 0; i < 4; ++i)
            #pragma unroll
            for (int r = 0; r < 4; ++r) {
                const float od = __shfl_xor(rb_d[i][r], off, 64);
                const int   oi = __shfl_xor(rb_i[i][r], off, 64);
                if (od < rb_d[i][r] || (od == rb_d[i][r] && oi < rb_i[i][r])) {
                    rb_d[i][r] = od; rb_i[i][r] = oi;
                }
            }
    }
    if (l16 == 0) {
        #pragma unroll
        for (int i = 0; i < 4; ++i)
            #pragma unroll
            for (int r = 0; r < 4; ++r) {
                const int m = wm * 64 + i * 16 + quad * 4 + r;   // 0..255
                s_wd[wn * BM + m] = rb_d[i][r];
                s_wi[wn * BM + m] = rb_i[i][r];
            }
    }
    __syncthreads();

    float bsum = 0.f;
    if (tid < BM) {
        float bd = s_wd[tid];
        int   bi = s_wi[tid];
        const float od = s_wd[BM + tid];
        const int   oi = s_wi[BM + tid];
        if (od < bd || (od == bd && oi < bi)) { bd = od; bi = oi; }
        s_wi[tid] = bi;                       // final index for gather
        out_idx[row0 + tid] = (float)bi;
        bsum = bd;                            // |x-v|^2_row = |x|^2_row + bd
    }
    __syncthreads();

    // epilogue: gather values (straight-through fwd == values)
    const int col = tid & 255;
    const int sub = tid >> 8;
    #pragma unroll 4
    for (int it = 0; it < 128; ++it) {
        const int r  = it * 2 + sub;
        const int bi = s_wi[r];
        out_vals[(size_t)(row0 + r) * D + col] = E[(size_t)bi * D + col];
    }

    // loss: sum(|x-v|^2) = sum|x|^2 + sum(min dist)
    float part = xs + bsum;
    #pragma unroll
    for (int off = 1; off < 64; off <<= 1) part += __shfl_xor(part, off, 64);
    if (lane == 0) s_red[w] = part;
    __syncthreads();
    if (tid == 0) {
        float tot = 0.f;
        #pragma unroll
        for (int i = 0; i < 8; ++i) tot += s_red[i];
        atomicAdd(out_loss, tot * (1.1f / 16777216.f));  // loss1 + 0.1*loss2
    }
}

extern "C" void kernel_launch(void* const* d_in, const int* in_sizes, int n_in,
                              void* d_out, int out_size, void* d_ws, size_t ws_size,
                              hipStream_t stream) {
    const float* X = (const float*)d_in[0];
    const float* E = (const float*)d_in[1];
    float* out      = (float*)d_out;
    float* out_vals = out;
    float* out_idx  = out + (size_t)BT * D;
    float* out_loss = out + (size_t)BT * D + BT;

    char* ws = (char*)d_ws;
    _Float16* Eh = (_Float16*)ws;
    _Float16* El = Eh + (size_t)KCB * D;
    float*    enorm = (float*)(El + (size_t)KCB * D);
    (void)ws_size; (void)n_in; (void)in_sizes; (void)out_size;

    hipMemsetAsync(out_loss, 0, sizeof(float), stream);  // d_out poisoned 0xAA
    split_e_kernel<<<KCB / 8, 256, 0, stream>>>(E, Eh, El, enorm);
    vq_mfma_kernel<<<BT / BM, 512, 0, stream>>>(X, E, Eh, El, enorm,
                                                out_vals, out_idx, out_loss);
}

// Round 3
// 239.088 us; speedup vs baseline: 1.6355x; 1.0210x over previous
//
#include <hip/hip_runtime.h>
#include <stdint.h>

// VQ-VAE quantize forward, MI355X. Split-f16 MFMA distance GEMM.
// R8: split moved OUT of the main loop (pre-split X -> Xh/Xl + xnorm, same
// pass as E). Main loop is pure staging+MFMA: 8 global_load_lds + 16
// ds_read_b128 + 48 MFMA per step. BM=BN=128, BK=32, 256 thr (4 waves,
// 2Mx2N), LDS 69KB -> 2 independent blocks/CU (phase diversity: one
// block's MFMA overlaps the other's loads — single-block R7 was barrier-
// lockstepped, VALU split phase serialized with MFMA phase => 26% MfmaUtil).
// Counted s_waitcnt vmcnt(8), raw s_barrier, setprio around MFMA (T5).
// Split math + MFMA order identical to R5/R7 -> bit-identical distances.
// out = [values (BT*D)] [indexes as float (BT)] [loss (1)]

#define BT    65536     // 16*4096 rows
#define D     256       // codeword size
#define KCB   1024      // codebook size
#define BM    128       // rows per block tile
#define BN    128       // cols per n-tile
#define NT    (KCB/BN)  // 8 col tiles
#define BK    32        // k chunk
#define NSTEP (NT * (D / BK))   // 64 pipelined steps

typedef float    f32x4 __attribute__((ext_vector_type(4)));
typedef _Float16 f16x8 __attribute__((ext_vector_type(8)));

#define GLOAD_LDS16(g, l) \
  __builtin_amdgcn_global_load_lds((const __attribute__((address_space(1))) void*)(g), \
                                   (__attribute__((address_space(3))) void*)(l), 16, 0, 0)

// ---- split src[nrows x 256] -> hi, lo f16 + fp32 row norms ----
__global__ __launch_bounds__(256) void split_kernel(const float* __restrict__ src,
                                                    _Float16* __restrict__ dh,
                                                    _Float16* __restrict__ dl,
                                                    float* __restrict__ norm) {
    const int r = blockIdx.x * 8 + (threadIdx.x >> 5);
    const size_t i0 = (size_t)r * D + (threadIdx.x & 31) * 8;
    float4 v0 = *(const float4*)(src + i0);
    float4 v1 = *(const float4*)(src + i0 + 4);
    float v[8] = {v0.x, v0.y, v0.z, v0.w, v1.x, v1.y, v1.z, v1.w};
    f16x8 h, l;
    float s = 0.f;
    #pragma unroll
    for (int j = 0; j < 8; ++j) {
        _Float16 hh = (_Float16)v[j];
        h[j] = hh;
        l[j] = (_Float16)(v[j] - (float)hh);
        s += v[j] * v[j];
    }
    *(f16x8*)(dh + i0) = h;
    *(f16x8*)(dl + i0) = l;
    #pragma unroll
    for (int off = 1; off < 32; off <<= 1) s += __shfl_xor(s, off, 64);
    if ((threadIdx.x & 31) == 0) norm[r] = s;
}

// ---- main: pipelined split-f16 MFMA + argmin + gather + loss ----
__global__ __launch_bounds__(256, 2) void vq_mfma_kernel(
    const _Float16* __restrict__ Xh, const _Float16* __restrict__ Xl,
    const _Float16* __restrict__ Eh, const _Float16* __restrict__ El,
    const float* __restrict__ enorm, const float* __restrict__ xnorm,
    const float* __restrict__ E,
    float* __restrict__ out_vals, float* __restrict__ out_idx,
    float* __restrict__ out_loss) {
    // all tiles: 64B rows = 4 x 16B slots; logical slot l of row r lives at
    // phys slot (l + (r>>1)) & 3  (R5-verified family; 2-way/free on reads)
    __shared__ __align__(16) _Float16 Ash[2][BM * BK];   // 2 x 8 KB
    __shared__ __align__(16) _Float16 Asl[2][BM * BK];   // 2 x 8 KB
    __shared__ __align__(16) _Float16 Bsh[2][BN * BK];   // 2 x 8 KB
    __shared__ __align__(16) _Float16 Bsl[2][BN * BK];   // 2 x 8 KB
    __shared__ float s_en[KCB];                          // 4 KB
    __shared__ float s_bd[BM];
    __shared__ int   s_bi[BM];
    __shared__ float s_red[4];

    const int tid  = threadIdx.x;
    const int w    = tid >> 6;        // wave 0..3
    const int lane = tid & 63;
    const int quad = lane >> 4;
    const int l16  = lane & 15;
    const int wm   = w >> 1;          // wave row group (0..1) -> rows wm*64..+63
    const int wn   = w & 1;           // wave col group (0..1) -> cols wn*64..+63
    const int row0 = blockIdx.x * BM;

    // staging lane constants (linear LDS dest = base + lane*16; swizzle folded
    // into the per-lane GLOBAL source address — both-sides-or-neither rule)
    const int sr = lane >> 2;                                 // row in 16-row chunk
    const int sk = ((((lane & 3) - (lane >> 3)) & 3) << 3);   // f16 offset in 32-k row
    // frag-read physical slot (row bases are multiples of 16 -> r&15 == l16)
    const int kob = ((quad + ((l16 >> 1) & 3)) & 3) << 3;

    // s_en fill
    #pragma unroll
    for (int t = 0; t < 4; ++t) s_en[tid + t * 256] = enorm[tid + t * 256];

    auto STAGE = [&](int buf, int s) {
        const int kb   = (s & 7) * BK;
        const int col0 = (s >> 3) * BN;
        #pragma unroll
        for (int t = 0; t < 2; ++t) {
            const int chunk = w * 2 + t;                 // 0..7 (16 rows each)
            const int gr = chunk * 16 + sr;
            const size_t ga = (size_t)(row0 + gr) * D + kb + sk;
            GLOAD_LDS16(Xh + ga, &Ash[buf][chunk * 512]);
            GLOAD_LDS16(Xl + ga, &Asl[buf][chunk * 512]);
            const size_t gb = (size_t)(col0 + gr) * D + kb + sk;
            GLOAD_LDS16(Eh + gb, &Bsh[buf][chunk * 512]);
            GLOAD_LDS16(El + gb, &Bsl[buf][chunk * 512]);
        }
    };  // 8 loads per thread per call

    float rb_d[4][4];
    int   rb_i[4][4];
    #pragma unroll
    for (int i = 0; i < 4; ++i)
        #pragma unroll
        for (int r = 0; r < 4; ++r) { rb_d[i][r] = 3.4e38f; rb_i[i][r] = 0; }
    f32x4 acc[4][4];

    STAGE(0, 0);
    asm volatile("s_waitcnt lgkmcnt(0)" ::: "memory");   // s_en writes done

    #pragma unroll 2
    for (int s = 0; s < NSTEP; ++s) {
        const int cur = s & 1;
        if (s + 1 < NSTEP) {
            STAGE(cur ^ 1, s + 1);                       // 8 loads in flight
            asm volatile("s_waitcnt vmcnt(8)" ::: "memory");  // drain prev step's 8
        } else {
            asm volatile("s_waitcnt vmcnt(0)" ::: "memory");
        }
        __builtin_amdgcn_s_barrier();                    // cur fully landed

        if ((s & 7) == 0) {
            #pragma unroll
            for (int i = 0; i < 4; ++i)
                #pragma unroll
                for (int j = 0; j < 4; ++j) acc[i][j] = (f32x4)0.0f;
        }

        const _Float16* Ah = Ash[cur];
        const _Float16* Al = Asl[cur];
        const _Float16* Bh = Bsh[cur];
        const _Float16* Bl = Bsl[cur];

        f16x8 ah[4], al[4];
        #pragma unroll
        for (int i = 0; i < 4; ++i) {
            const int ra = (wm * 64 + i * 16 + l16) * BK + kob;
            ah[i] = *(const f16x8*)&Ah[ra];
            al[i] = *(const f16x8*)&Al[ra];
        }

        __builtin_amdgcn_s_setprio(1);
        #pragma unroll
        for (int j = 0; j < 4; ++j) {
            const int n = (wn * 64 + j * 16 + l16) * BK + kob;
            const f16x8 bh = *(const f16x8*)&Bh[n];
            const f16x8 bl = *(const f16x8*)&Bl[n];
            #pragma unroll
            for (int i = 0; i < 4; ++i) {
                acc[i][j] = __builtin_amdgcn_mfma_f32_16x16x32_f16(ah[i], bh, acc[i][j], 0, 0, 0);
                acc[i][j] = __builtin_amdgcn_mfma_f32_16x16x32_f16(al[i], bh, acc[i][j], 0, 0, 0);
                acc[i][j] = __builtin_amdgcn_mfma_f32_16x16x32_f16(ah[i], bl, acc[i][j], 0, 0, 0);
            }
        }
        __builtin_amdgcn_s_setprio(0);

        if ((s & 7) == 7) {                 // nt complete: fold argmin
            const int nt = s >> 3;
            #pragma unroll
            for (int j = 0; j < 4; ++j) {
                const int c = nt * BN + wn * 64 + j * 16 + l16;
                const float en = s_en[c];
                #pragma unroll
                for (int i = 0; i < 4; ++i)
                    #pragma unroll
                    for (int r = 0; r < 4; ++r) {
                        const float sd = en - 2.0f * acc[i][j][r];
                        if (sd < rb_d[i][r]) { rb_d[i][r] = sd; rb_i[i][r] = c; }
                    }
            }
        }
        __builtin_amdgcn_s_barrier();       // all waves done reading cur
    }

    // fold the 16 lanes of each quad (they partition this wave's col slice)
    #pragma unroll
    for (int off = 1; off < 16; off <<= 1) {
        #pragma unroll
        for (int i = 0; i < 4; ++i)
            #pragma unroll
            for (int r = 0; r < 4; ++r) {
                const float od = __shfl_xor(rb_d[i][r], off, 64);
                const int   oi = __shfl_xor(rb_i[i][r], off, 64);
                if (od < rb_d[i][r] || (od == rb_d[i][r] && oi < rb_i[i][r])) {
                    rb_d[i][r] = od; rb_i[i][r] = oi;
                }
            }
    }
    // two-phase deterministic merge of the wn=0 / wn=1 halves
    if (wn == 0 && l16 == 0) {
        #pragma unroll
        for (int i = 0; i < 4; ++i)
            #pragma unroll
            for (int r = 0; r < 4; ++r) {
                const int m = wm * 64 + i * 16 + quad * 4 + r;
                s_bd[m] = rb_d[i][r]; s_bi[m] = rb_i[i][r];
            }
    }
    __syncthreads();
    if (wn == 1 && l16 == 0) {
        #pragma unroll
        for (int i = 0; i < 4; ++i)
            #pragma unroll
            for (int r = 0; r < 4; ++r) {
                const int m = wm * 64 + i * 16 + quad * 4 + r;
                if (rb_d[i][r] < s_bd[m] || (rb_d[i][r] == s_bd[m] && rb_i[i][r] < s_bi[m])) {
                    s_bd[m] = rb_d[i][r]; s_bi[m] = rb_i[i][r];
                }
            }
    }
    __syncthreads();

    // epilogue: indexes + loss partial (sum|x|^2 + min dist), then gather
    float part = 0.f;
    if (tid < BM) {
        out_idx[row0 + tid] = (float)s_bi[tid];
        part = xnorm[row0 + tid] + s_bd[tid];
    }

    #pragma unroll 4
    for (int r = 0; r < BM; ++r) {
        const int bi = s_bi[r];
        out_vals[(size_t)(row0 + r) * D + tid] = E[(size_t)bi * D + tid];
    }

    #pragma unroll
    for (int off = 1; off < 64; off <<= 1) part += __shfl_xor(part, off, 64);
    if (lane == 0) s_red[w] = part;
    __syncthreads();
    if (tid == 0) {
        const float total = s_red[0] + s_red[1] + s_red[2] + s_red[3];
        atomicAdd(out_loss, total * (1.1f / 16777216.f));  // loss1 + 0.1*loss2
    }
}

extern "C" void kernel_launch(void* const* d_in, const int* in_sizes, int n_in,
                              void* d_out, int out_size, void* d_ws, size_t ws_size,
                              hipStream_t stream) {
    const float* X = (const float*)d_in[0];
    const float* E = (const float*)d_in[1];
    float* out      = (float*)d_out;
    float* out_vals = out;
    float* out_idx  = out + (size_t)BT * D;
    float* out_loss = out + (size_t)BT * D + BT;

    char* ws = (char*)d_ws;
    _Float16* Eh = (_Float16*)ws;
    _Float16* El    = Eh + (size_t)KCB * D;
    _Float16* Xh    = El + (size_t)KCB * D;
    _Float16* Xl    = Xh + (size_t)BT * D;
    float*    enorm = (float*)(Xl + (size_t)BT * D);
    float*    xnorm = enorm + KCB;
    (void)ws_size; (void)n_in; (void)in_sizes; (void)out_size;

    hipMemsetAsync(out_loss, 0, sizeof(float), stream);  // d_out poisoned 0xAA
    split_kernel<<<KCB / 8, 256, 0, stream>>>(E, Eh, El, enorm);
    split_kernel<<<BT / 8, 256, 0, stream>>>(X, Xh, Xl, xnorm);
    vq_mfma_kernel<<<BT / BM, 256, 0, stream>>>(Xh, Xl, Eh, El, enorm, xnorm, E,
                                                out_vals, out_idx, out_loss);
}

// Round 4
// 228.825 us; speedup vs baseline: 1.7088x; 1.0448x over previous
//
#include <hip/hip_runtime.h>
#include <stdint.h>

// VQ-VAE quantize forward, MI355X. Split-f16 MFMA distance GEMM.
// R9: 256x256x32 tile, 8 waves (512 thr, wave tile 64x128, 4Mx2N),
// grid=256 = 1 block/CU, zero tail. Staged bytes halve vs R8
// (64MBx4 + 1MBx256 = 512MB); step compute ~3725cy covers HBM latency
// 4x (R8's 1200cy was marginal). Same R8-proven mechanics: pre-split
// X/E to f16 hi/lo, global_load_lds staging with R5-verified
// (c+(r>>1))&3 swizzle on 64B rows, counted s_waitcnt vmcnt(8), raw
// s_barrier, setprio around MFMA. kc-ascending accumulation + MFMA
// order (hh,lh,hl) identical -> bit-identical distances/argmin.
// out = [values (BT*D)] [indexes as float (BT)] [loss (1)]

#define BT    65536     // 16*4096 rows
#define D     256       // codeword size
#define KCB   1024      // codebook size
#define BM    256       // rows per block tile
#define BN    256       // cols per n-tile
#define NT    (KCB/BN)  // 4 col tiles
#define BK    32        // k chunk
#define NSTEP (NT * (D / BK))   // 32 pipelined steps

typedef float    f32x4 __attribute__((ext_vector_type(4)));
typedef _Float16 f16x8 __attribute__((ext_vector_type(8)));

#define GLOAD_LDS16(g, l) \
  __builtin_amdgcn_global_load_lds((const __attribute__((address_space(1))) void*)(g), \
                                   (__attribute__((address_space(3))) void*)(l), 16, 0, 0)

// ---- split src[nrows x 256] -> hi, lo f16 + fp32 row norms ----
__global__ __launch_bounds__(256) void split_kernel(const float* __restrict__ src,
                                                    _Float16* __restrict__ dh,
                                                    _Float16* __restrict__ dl,
                                                    float* __restrict__ norm) {
    const int r = blockIdx.x * 8 + (threadIdx.x >> 5);
    const size_t i0 = (size_t)r * D + (threadIdx.x & 31) * 8;
    float4 v0 = *(const float4*)(src + i0);
    float4 v1 = *(const float4*)(src + i0 + 4);
    float v[8] = {v0.x, v0.y, v0.z, v0.w, v1.x, v1.y, v1.z, v1.w};
    f16x8 h, l;
    float s = 0.f;
    #pragma unroll
    for (int j = 0; j < 8; ++j) {
        _Float16 hh = (_Float16)v[j];
        h[j] = hh;
        l[j] = (_Float16)(v[j] - (float)hh);
        s += v[j] * v[j];
    }
    *(f16x8*)(dh + i0) = h;
    *(f16x8*)(dl + i0) = l;
    #pragma unroll
    for (int off = 1; off < 32; off <<= 1) s += __shfl_xor(s, off, 64);
    if ((threadIdx.x & 31) == 0) norm[r] = s;
}

// ---- main: pipelined split-f16 MFMA + argmin + gather + loss ----
__global__ __launch_bounds__(512, 2) void vq_mfma_kernel(
    const _Float16* __restrict__ Xh, const _Float16* __restrict__ Xl,
    const _Float16* __restrict__ Eh, const _Float16* __restrict__ El,
    const float* __restrict__ enorm, const float* __restrict__ xnorm,
    const float* __restrict__ E,
    float* __restrict__ out_vals, float* __restrict__ out_idx,
    float* __restrict__ out_loss) {
    // all tiles: 64B rows = 4 x 16B slots; logical slot l of row r lives at
    // phys slot (l + (r>>1)) & 3  (R5/R8-verified; 2-way/free on reads)
    __shared__ __align__(16) _Float16 Ash[2][BM * BK];   // 2 x 16 KB
    __shared__ __align__(16) _Float16 Asl[2][BM * BK];   // 2 x 16 KB
    __shared__ __align__(16) _Float16 Bsh[2][BN * BK];   // 2 x 16 KB
    __shared__ __align__(16) _Float16 Bsl[2][BN * BK];   // 2 x 16 KB
    __shared__ float s_en[KCB];                          // 4 KB
    __shared__ float s_bd[BM];                           // 1 KB
    __shared__ int   s_bi[BM];                           // 1 KB
    __shared__ float s_red[8];

    const int tid  = threadIdx.x;
    const int w    = tid >> 6;        // wave 0..7
    const int lane = tid & 63;
    const int quad = lane >> 4;
    const int l16  = lane & 15;
    const int wm   = w >> 1;          // wave row group (0..3) -> rows wm*64..+63
    const int wn   = w & 1;           // wave col group (0..1) -> cols wn*128..+127
    const int row0 = blockIdx.x * BM;

    // staging lane constants (linear LDS dest = base + lane*16; swizzle folded
    // into the per-lane GLOBAL source address — both-sides-or-neither rule)
    const int sr = lane >> 2;                                 // row in 16-row chunk
    const int sk = ((((lane & 3) - (lane >> 3)) & 3) << 3);   // f16 offset in 32-k row
    // frag-read physical slot (row bases are multiples of 16 -> r&15 == l16)
    const int kob = ((quad + ((l16 >> 1) & 3)) & 3) << 3;

    // s_en fill
    s_en[tid]       = enorm[tid];
    s_en[tid + 512] = enorm[tid + 512];

    auto STAGE = [&](int buf, int s) {
        const int kb   = (s & 7) * BK;
        const int col0 = (s >> 3) * BN;
        #pragma unroll
        for (int t = 0; t < 2; ++t) {
            const int chunk = w * 2 + t;                 // 0..15 (16 rows each)
            const int gr = chunk * 16 + sr;
            const size_t ga = (size_t)(row0 + gr) * D + kb + sk;
            GLOAD_LDS16(Xh + ga, &Ash[buf][chunk * 512]);
            GLOAD_LDS16(Xl + ga, &Asl[buf][chunk * 512]);
            const size_t gb = (size_t)(col0 + gr) * D + kb + sk;
            GLOAD_LDS16(Eh + gb, &Bsh[buf][chunk * 512]);
            GLOAD_LDS16(El + gb, &Bsl[buf][chunk * 512]);
        }
    };  // 8 loads per thread per call

    float rb_d[4][4];
    int   rb_i[4][4];
    #pragma unroll
    for (int i = 0; i < 4; ++i)
        #pragma unroll
        for (int r = 0; r < 4; ++r) { rb_d[i][r] = 3.4e38f; rb_i[i][r] = 0; }
    f32x4 acc[4][8];

    STAGE(0, 0);
    asm volatile("s_waitcnt lgkmcnt(0)" ::: "memory");   // s_en writes done

    #pragma unroll 2
    for (int s = 0; s < NSTEP; ++s) {
        const int cur = s & 1;
        if (s + 1 < NSTEP) {
            STAGE(cur ^ 1, s + 1);                       // 8 loads in flight
            asm volatile("s_waitcnt vmcnt(8)" ::: "memory");  // drain prev step's 8
        } else {
            asm volatile("s_waitcnt vmcnt(0)" ::: "memory");
        }
        __builtin_amdgcn_s_barrier();                    // cur fully landed

        if ((s & 7) == 0) {
            #pragma unroll
            for (int i = 0; i < 4; ++i)
                #pragma unroll
                for (int j = 0; j < 8; ++j) acc[i][j] = (f32x4)0.0f;
        }

        const _Float16* Ah = Ash[cur];
        const _Float16* Al = Asl[cur];
        const _Float16* Bh = Bsh[cur];
        const _Float16* Bl = Bsl[cur];

        f16x8 ah[4], al[4];
        #pragma unroll
        for (int i = 0; i < 4; ++i) {
            const int ra = (wm * 64 + i * 16 + l16) * BK + kob;
            ah[i] = *(const f16x8*)&Ah[ra];
            al[i] = *(const f16x8*)&Al[ra];
        }

        __builtin_amdgcn_s_setprio(1);
        #pragma unroll
        for (int j = 0; j < 8; ++j) {
            const int n = (wn * 128 + j * 16 + l16) * BK + kob;
            const f16x8 bh = *(const f16x8*)&Bh[n];
            const f16x8 bl = *(const f16x8*)&Bl[n];
            #pragma unroll
            for (int i = 0; i < 4; ++i) {
                acc[i][j] = __builtin_amdgcn_mfma_f32_16x16x32_f16(ah[i], bh, acc[i][j], 0, 0, 0);
                acc[i][j] = __builtin_amdgcn_mfma_f32_16x16x32_f16(al[i], bh, acc[i][j], 0, 0, 0);
                acc[i][j] = __builtin_amdgcn_mfma_f32_16x16x32_f16(ah[i], bl, acc[i][j], 0, 0, 0);
            }
        }
        __builtin_amdgcn_s_setprio(0);

        if ((s & 7) == 7) {                 // nt complete: fold argmin
            const int nt = s >> 3;
            #pragma unroll
            for (int j = 0; j < 8; ++j) {
                const int c = nt * BN + wn * 128 + j * 16 + l16;
                const float en = s_en[c];
                #pragma unroll
                for (int i = 0; i < 4; ++i)
                    #pragma unroll
                    for (int r = 0; r < 4; ++r) {
                        const float sd = en - 2.0f * acc[i][j][r];
                        if (sd < rb_d[i][r]) { rb_d[i][r] = sd; rb_i[i][r] = c; }
                    }
            }
        }
        __builtin_amdgcn_s_barrier();       // all waves done reading cur
    }

    // fold the 16 lanes of each quad (they partition this wave's col slice)
    #pragma unroll
    for (int off = 1; off < 16; off <<= 1) {
        #pragma unroll
        for (int i = 0; i < 4; ++i)
            #pragma unroll
            for (int r = 0; r < 4; ++r) {
                const float od = __shfl_xor(rb_d[i][r], off, 64);
                const int   oi = __shfl_xor(rb_i[i][r], off, 64);
                if (od < rb_d[i][r] || (od == rb_d[i][r] && oi < rb_i[i][r])) {
                    rb_d[i][r] = od; rb_i[i][r] = oi;
                }
            }
    }
    // two-phase deterministic merge of the wn=0 / wn=1 halves
    if (wn == 0 && l16 == 0) {
        #pragma unroll
        for (int i = 0; i < 4; ++i)
            #pragma unroll
            for (int r = 0; r < 4; ++r) {
                const int m = wm * 64 + i * 16 + quad * 4 + r;
                s_bd[m] = rb_d[i][r]; s_bi[m] = rb_i[i][r];
            }
    }
    __syncthreads();
    if (wn == 1 && l16 == 0) {
        #pragma unroll
        for (int i = 0; i < 4; ++i)
            #pragma unroll
            for (int r = 0; r < 4; ++r) {
                const int m = wm * 64 + i * 16 + quad * 4 + r;
                if (rb_d[i][r] < s_bd[m] || (rb_d[i][r] == s_bd[m] && rb_i[i][r] < s_bi[m])) {
                    s_bd[m] = rb_d[i][r]; s_bi[m] = rb_i[i][r];
                }
            }
    }
    __syncthreads();

    // epilogue: indexes + loss partial (sum|x|^2 + min dist), then gather
    float part = 0.f;
    if (tid < BM) {
        out_idx[row0 + tid] = (float)s_bi[tid];
        part = xnorm[row0 + tid] + s_bd[tid];
    }

    const int col = tid & 255;
    const int sub = tid >> 8;
    #pragma unroll 4
    for (int it = 0; it < BM / 2; ++it) {
        const int r  = it * 2 + sub;
        const int bi = s_bi[r];
        out_vals[(size_t)(row0 + r) * D + col] = E[(size_t)bi * D + col];
    }

    #pragma unroll
    for (int off = 1; off < 64; off <<= 1) part += __shfl_xor(part, off, 64);
    if (lane == 0) s_red[w] = part;
    __syncthreads();
    if (tid == 0) {
        float tot = 0.f;
        #pragma unroll
        for (int i = 0; i < 8; ++i) tot += s_red[i];
        atomicAdd(out_loss, tot * (1.1f / 16777216.f));  // loss1 + 0.1*loss2
    }
}

extern "C" void kernel_launch(void* const* d_in, const int* in_sizes, int n_in,
                              void* d_out, int out_size, void* d_ws, size_t ws_size,
                              hipStream_t stream) {
    const float* X = (const float*)d_in[0];
    const float* E = (const float*)d_in[1];
    float* out      = (float*)d_out;
    float* out_vals = out;
    float* out_idx  = out + (size_t)BT * D;
    float* out_loss = out + (size_t)BT * D + BT;

    char* ws = (char*)d_ws;
    _Float16* Eh    = (_Float16*)ws;
    _Float16* El    = Eh + (size_t)KCB * D;
    _Float16* Xh    = El + (size_t)KCB * D;
    _Float16* Xl    = Xh + (size_t)BT * D;
    float*    enorm = (float*)(Xl + (size_t)BT * D);
    float*    xnorm = enorm + KCB;
    (void)ws_size; (void)n_in; (void)in_sizes; (void)out_size;

    hipMemsetAsync(out_loss, 0, sizeof(float), stream);  // d_out poisoned 0xAA
    split_kernel<<<KCB / 8, 256, 0, stream>>>(E, Eh, El, enorm);
    split_kernel<<<BT / 8, 256, 0, stream>>>(X, Xh, Xl, xnorm);
    vq_mfma_kernel<<<BT / BM, 512, 0, stream>>>(Xh, Xl, Eh, El, enorm, xnorm, E,
                                                out_vals, out_idx, out_loss);
}

// Round 5
// 217.302 us; speedup vs baseline: 1.7995x; 1.0530x over previous
//
#include <hip/hip_runtime.h>
#include <stdint.h>

// VQ-VAE quantize forward, MI355X. Split-f16 MFMA distance GEMM.
// R10: 4-phase interleaved step (m201 template): per phase {ds_read j-pair
// B frags; s_barrier; lgkmcnt(0)+sched_barrier; setprio(1); 24 MFMA;
// setprio(0); s_barrier}. Counted vmcnt(8) staging kept (all 8 loads at
// step start, 1-step lookahead, 2 LDS buffers). A staged as fp32 via
// global_load_lds with R5-verified c^(r&7) 128B-row swizzle, split to f16
// hi/lo in-register after ds_read (R5 code) -> split_x kernel eliminated;
// sum|x|^2 accumulated in-register at nt==0. memset folded into split_e.
// 2 dispatches total. Distances bit-identical to R5..R9 (same split math,
// same per-acc MFMA order hh,lh,hl, same kc order).
// out = [values (BT*D)] [indexes as float (BT)] [loss (1)]

#define BT    65536     // 16*4096 rows
#define D     256       // codeword size
#define KCB   1024      // codebook size
#define BM    256       // rows per block tile
#define BN    256       // cols per n-tile
#define NT    (KCB/BN)  // 4 col tiles
#define BK    32        // k chunk
#define NSTEP (NT * (D / BK))   // 32 pipelined steps

typedef float    f32x4 __attribute__((ext_vector_type(4)));
typedef _Float16 f16x8 __attribute__((ext_vector_type(8)));

#define GLOAD_LDS16(g, l) \
  __builtin_amdgcn_global_load_lds((const __attribute__((address_space(1))) void*)(g), \
                                   (__attribute__((address_space(3))) void*)(l), 16, 0, 0)

// ---- split E -> Eh, El + fp32 |e|^2; also zeroes out_loss (1MB in; ~3us) ----
__global__ __launch_bounds__(256) void split_e_kernel(const float* __restrict__ E,
                                                      _Float16* __restrict__ Eh,
                                                      _Float16* __restrict__ El,
                                                      float* __restrict__ enorm,
                                                      float* __restrict__ out_loss) {
    if (blockIdx.x == 0 && threadIdx.x == 0) *out_loss = 0.f;
    const int r = blockIdx.x * 8 + (threadIdx.x >> 5);
    const size_t i0 = (size_t)r * D + (threadIdx.x & 31) * 8;
    float4 v0 = *(const float4*)(E + i0);
    float4 v1 = *(const float4*)(E + i0 + 4);
    float v[8] = {v0.x, v0.y, v0.z, v0.w, v1.x, v1.y, v1.z, v1.w};
    f16x8 h, l;
    float s = 0.f;
    #pragma unroll
    for (int j = 0; j < 8; ++j) {
        _Float16 hh = (_Float16)v[j];
        h[j] = hh;
        l[j] = (_Float16)(v[j] - (float)hh);
        s += v[j] * v[j];
    }
    *(f16x8*)(Eh + i0) = h;
    *(f16x8*)(El + i0) = l;
    #pragma unroll
    for (int off = 1; off < 32; off <<= 1) s += __shfl_xor(s, off, 64);
    if ((threadIdx.x & 31) == 0) enorm[r] = s;
}

// ---- main: 4-phase pipelined split-f16 MFMA + argmin + gather + loss ----
__global__ __launch_bounds__(512, 2) void vq_mfma_kernel(
    const float* __restrict__ X,
    const _Float16* __restrict__ Eh, const _Float16* __restrict__ El,
    const float* __restrict__ enorm, const float* __restrict__ E,
    float* __restrict__ out_vals, float* __restrict__ out_idx,
    float* __restrict__ out_loss) {
    // A: fp32, 128B rows = 8 x 16B chunks, phys chunk = c ^ (r&7) (R5-verified).
    // B: f16 hi/lo, 64B rows = 4 x 16B slots, phys = (c + (r>>1)) & 3 (R5-verified).
    __shared__ __align__(16) float    Asf[2][BM * BK];   // 2 x 32 KB fp32 A
    __shared__ __align__(16) _Float16 Bsh[2][BN * BK];   // 2 x 16 KB
    __shared__ __align__(16) _Float16 Bsl[2][BN * BK];   // 2 x 16 KB
    __shared__ float s_en[KCB];                          // 4 KB
    __shared__ float s_bd[BM];                           // 1 KB
    __shared__ int   s_bi[BM];                           // 1 KB
    __shared__ float s_red[8];

    const int tid  = threadIdx.x;
    const int w    = tid >> 6;        // wave 0..7
    const int lane = tid & 63;
    const int quad = lane >> 4;
    const int l16  = lane & 15;
    const int wm   = w >> 1;          // wave row group (0..3) -> rows wm*64..+63
    const int wn   = w & 1;           // wave col group (0..1) -> cols wn*128..+127
    const int sxa  = l16 & 7;         // A frag-read row swizzle (r&7 == l16&7)
    const int row0 = blockIdx.x * BM;

    // A staging: 32 chunks of 1KB (8 fp32 rows each); wave w owns chunks w*4..+3.
    const int sa_row = lane >> 3;
    const int sa_off = ((lane & 7) ^ sa_row) * 4;             // float offset in 32-k row
    // B staging: 16 chunks of 1KB (16 f16 rows each); wave w owns chunks w*2, w*2+1.
    const int sb_row = lane >> 2;
    const int sb_off = ((((lane & 3) - (lane >> 3)) & 3) << 3);   // f16 offset
    // B frag-read physical slot (col bases are multiples of 16 -> r&15 == l16)
    const int kob = ((quad + ((l16 >> 1) & 3)) & 3) << 3;

    // s_en fill
    s_en[tid]       = enorm[tid];
    s_en[tid + 512] = enorm[tid + 512];

    auto STAGE = [&](int buf, int s) {
        const int kb   = (s & 7) * BK;
        const int col0 = (s >> 3) * BN;
        #pragma unroll
        for (int t = 0; t < 4; ++t) {
            const int chunk = w * 4 + t;                 // 0..31 (8 fp32 rows each)
            const int gr = row0 + chunk * 8 + sa_row;
            GLOAD_LDS16(X + (size_t)gr * D + kb + sa_off, &Asf[buf][chunk * 256]);
        }
        #pragma unroll
        for (int t = 0; t < 2; ++t) {
            const int chunk = w * 2 + t;                 // 0..15 (16 f16 rows each)
            const int gr = col0 + chunk * 16 + sb_row;
            const size_t gb = (size_t)gr * D + kb + sb_off;
            GLOAD_LDS16(Eh + gb, &Bsh[buf][chunk * 512]);
            GLOAD_LDS16(El + gb, &Bsl[buf][chunk * 512]);
        }
    };  // 8 loads per thread per call

    float rb_d[4][4];
    int   rb_i[4][4];
    #pragma unroll
    for (int i = 0; i < 4; ++i)
        #pragma unroll
        for (int r = 0; r < 4; ++r) { rb_d[i][r] = 3.4e38f; rb_i[i][r] = 0; }
    float xs = 0.f;               // sum of x^2 (each element once: nt==0, wn==0)
    f32x4 acc[4][8];

    STAGE(0, 0);
    asm volatile("s_waitcnt lgkmcnt(0)" ::: "memory");   // s_en writes done

    #pragma unroll 2
    for (int s = 0; s < NSTEP; ++s) {
        const int cur = s & 1;
        if (s + 1 < NSTEP) {
            STAGE(cur ^ 1, s + 1);                       // 8 loads in flight
            asm volatile("s_waitcnt vmcnt(8)" ::: "memory");  // prev step's 8 landed
        } else {
            asm volatile("s_waitcnt vmcnt(0)" ::: "memory");
        }
        __builtin_amdgcn_s_barrier();                    // cur valid block-wide

        if ((s & 7) == 0) {
            #pragma unroll
            for (int i = 0; i < 4; ++i)
                #pragma unroll
                for (int j = 0; j < 8; ++j) acc[i][j] = (f32x4)0.0f;
        }

        const float*    As = Asf[cur];
        const _Float16* Bh = Bsh[cur];
        const _Float16* Bl = Bsl[cur];

        // A frags: read fp32, split to f16 hi/lo in-register (R5-verified path)
        f16x8 ah[4], al[4];
        #pragma unroll
        for (int i = 0; i < 4; ++i) {
            const float* rp = As + (wm * 64 + i * 16 + l16) * BK;
            const f32x4 v0 = *(const f32x4*)(rp + ((((quad << 1))     ^ sxa) << 2));
            const f32x4 v1 = *(const f32x4*)(rp + ((((quad << 1) | 1) ^ sxa) << 2));
            const float f[8] = {v0.x, v0.y, v0.z, v0.w, v1.x, v1.y, v1.z, v1.w};
            #pragma unroll
            for (int e = 0; e < 8; ++e) {
                const _Float16 hh = (_Float16)f[e];
                ah[i][e] = hh;
                al[i][e] = (_Float16)(f[e] - (float)hh);
            }
            if (wn == 0 && s < 8) {
                #pragma unroll
                for (int e = 0; e < 8; ++e) xs += f[e] * f[e];
            }
        }

        // ---- 4 phases: {read j-pair B frags; bar; lgkm0; prio1; 24 MFMA; prio0; bar}
        #pragma unroll
        for (int jp = 0; jp < 4; ++jp) {
            const int j0 = jp * 2, j1 = jp * 2 + 1;
            const f16x8 bh0 = *(const f16x8*)&Bh[(wn * 128 + j0 * 16 + l16) * BK + kob];
            const f16x8 bl0 = *(const f16x8*)&Bl[(wn * 128 + j0 * 16 + l16) * BK + kob];
            const f16x8 bh1 = *(const f16x8*)&Bh[(wn * 128 + j1 * 16 + l16) * BK + kob];
            const f16x8 bl1 = *(const f16x8*)&Bl[(wn * 128 + j1 * 16 + l16) * BK + kob];
            __builtin_amdgcn_s_barrier();
            asm volatile("s_waitcnt lgkmcnt(0)" ::: "memory");
            __builtin_amdgcn_sched_barrier(0);           // rule #18: pin MFMA below wait
            __builtin_amdgcn_s_setprio(1);
            #pragma unroll
            for (int i = 0; i < 4; ++i) {
                acc[i][j0] = __builtin_amdgcn_mfma_f32_16x16x32_f16(ah[i], bh0, acc[i][j0], 0, 0, 0);
                acc[i][j0] = __builtin_amdgcn_mfma_f32_16x16x32_f16(al[i], bh0, acc[i][j0], 0, 0, 0);
                acc[i][j0] = __builtin_amdgcn_mfma_f32_16x16x32_f16(ah[i], bl0, acc[i][j0], 0, 0, 0);
            }
            #pragma unroll
            for (int i = 0; i < 4; ++i) {
                acc[i][j1] = __builtin_amdgcn_mfma_f32_16x16x32_f16(ah[i], bh1, acc[i][j1], 0, 0, 0);
                acc[i][j1] = __builtin_amdgcn_mfma_f32_16x16x32_f16(al[i], bh1, acc[i][j1], 0, 0, 0);
                acc[i][j1] = __builtin_amdgcn_mfma_f32_16x16x32_f16(ah[i], bl1, acc[i][j1], 0, 0, 0);
            }
            __builtin_amdgcn_s_setprio(0);
            __builtin_amdgcn_s_barrier();   // phase done; last one = write-safety
        }

        if ((s & 7) == 7) {                 // nt complete: fold argmin
            const int nt = s >> 3;
            #pragma unroll
            for (int j = 0; j < 8; ++j) {
                const int c = nt * BN + wn * 128 + j * 16 + l16;
                const float en = s_en[c];
                #pragma unroll
                for (int i = 0; i < 4; ++i)
                    #pragma unroll
                    for (int r = 0; r < 4; ++r) {
                        const float sd = en - 2.0f * acc[i][j][r];
                        if (sd < rb_d[i][r]) { rb_d[i][r] = sd; rb_i[i][r] = c; }
                    }
            }
        }
    }

    // fold the 16 lanes of each quad (they partition this wave's col slice)
    #pragma unroll
    for (int off = 1; off < 16; off <<= 1) {
        #pragma unroll
        for (int i = 0; i < 4; ++i)
            #pragma unroll
            for (int r = 0; r < 4; ++r) {
                const float od = __shfl_xor(rb_d[i][r], off, 64);
                const int   oi = __shfl_xor(rb_i[i][r], off, 64);
                if (od < rb_d[i][r] || (od == rb_d[i][r] && oi < rb_i[i][r])) {
                    rb_d[i][r] = od; rb_i[i][r] = oi;
                }
            }
    }
    // two-phase deterministic merge of the wn=0 / wn=1 halves
    if (wn == 0 && l16 == 0) {
        #pragma unroll
        for (int i = 0; i < 4; ++i)
            #pragma unroll
            for (int r = 0; r < 4; ++r) {
                const int m = wm * 64 + i * 16 + quad * 4 + r;
                s_bd[m] = rb_d[i][r]; s_bi[m] = rb_i[i][r];
            }
    }
    __syncthreads();
    if (wn == 1 && l16 == 0) {
        #pragma unroll
        for (int i = 0; i < 4; ++i)
            #pragma unroll
            for (int r = 0; r < 4; ++r) {
                const int m = wm * 64 + i * 16 + quad * 4 + r;
                if (rb_d[i][r] < s_bd[m] || (rb_d[i][r] == s_bd[m] && rb_i[i][r] < s_bi[m])) {
                    s_bd[m] = rb_d[i][r]; s_bi[m] = rb_i[i][r];
                }
            }
    }
    __syncthreads();

    // epilogue: indexes + loss partial (sum|x|^2 + min dist), then gather
    float part = xs;
    if (tid < BM) {
        out_idx[row0 + tid] = (float)s_bi[tid];
        part += s_bd[tid];
    }

    const int col = tid & 255;
    const int sub = tid >> 8;
    #pragma unroll 4
    for (int it = 0; it < BM / 2; ++it) {
        const int r  = it * 2 + sub;
        const int bi = s_bi[r];
        out_vals[(size_t)(row0 + r) * D + col] = E[(size_t)bi * D + col];
    }

    #pragma unroll
    for (int off = 1; off < 64; off <<= 1) part += __shfl_xor(part, off, 64);
    if (lane == 0) s_red[w] = part;
    __syncthreads();
    if (tid == 0) {
        float tot = 0.f;
        #pragma unroll
        for (int i = 0; i < 8; ++i) tot += s_red[i];
        atomicAdd(out_loss, tot * (1.1f / 16777216.f));  // loss1 + 0.1*loss2
    }
}

extern "C" void kernel_launch(void* const* d_in, const int* in_sizes, int n_in,
                              void* d_out, int out_size, void* d_ws, size_t ws_size,
                              hipStream_t stream) {
    const float* X = (const float*)d_in[0];
    const float* E = (const float*)d_in[1];
    float* out      = (float*)d_out;
    float* out_vals = out;
    float* out_idx  = out + (size_t)BT * D;
    float* out_loss = out + (size_t)BT * D + BT;

    char* ws = (char*)d_ws;
    _Float16* Eh    = (_Float16*)ws;
    _Float16* El    = Eh + (size_t)KCB * D;
    float*    enorm = (float*)(El + (size_t)KCB * D);
    (void)ws_size; (void)n_in; (void)in_sizes; (void)out_size;

    split_e_kernel<<<KCB / 8, 256, 0, stream>>>(E, Eh, El, enorm, out_loss);
    vq_mfma_kernel<<<BT / BM, 512, 0, stream>>>(X, Eh, El, enorm, E,
                                                out_vals, out_idx, out_loss);
}

// Round 6
// 211.281 us; speedup vs baseline: 1.8507x; 1.0285x over previous
//
#include <hip/hip_runtime.h>
#include <stdint.h>

// VQ-VAE quantize forward, MI355X. Split-f16 MFMA distance GEMM.
// R11 = R9's loop structure (proven 123us main: 2 barriers/step, counted
// s_waitcnt vmcnt(8), whole-step compiler-scheduled body, setprio around
// the full MFMA cluster) + R10's dispatch structure (A staged fp32 via
// global_load_lds with R5-verified c^(r&7) swizzle, split to f16 hi/lo
// in-register after ds_read; sum|x|^2 in-register; loss-zero folded into
// split_e -> 2 dispatches, no split_x kernel). R10's 4-phase barriers +
// sched_barrier(0) removed (isolated -14us regression: 8 full-block
// barriers/step around 24-MFMA clusters + order-pinning, m141 mode).
// Distances bit-identical to R5..R10 (same split math, same hh/lh/hl
// order, same kc order) -> identical argmin/absmax.
// out = [values (BT*D)] [indexes as float (BT)] [loss (1)]

#define BT    65536     // 16*4096 rows
#define D     256       // codeword size
#define KCB   1024      // codebook size
#define BM    256       // rows per block tile
#define BN    256       // cols per n-tile
#define NT    (KCB/BN)  // 4 col tiles
#define BK    32        // k chunk
#define NSTEP (NT * (D / BK))   // 32 pipelined steps

typedef float    f32x4 __attribute__((ext_vector_type(4)));
typedef _Float16 f16x8 __attribute__((ext_vector_type(8)));

#define GLOAD_LDS16(g, l) \
  __builtin_amdgcn_global_load_lds((const __attribute__((address_space(1))) void*)(g), \
                                   (__attribute__((address_space(3))) void*)(l), 16, 0, 0)

// ---- split E -> Eh, El + fp32 |e|^2; also zeroes out_loss (1MB in; ~3us) ----
__global__ __launch_bounds__(256) void split_e_kernel(const float* __restrict__ E,
                                                      _Float16* __restrict__ Eh,
                                                      _Float16* __restrict__ El,
                                                      float* __restrict__ enorm,
                                                      float* __restrict__ out_loss) {
    if (blockIdx.x == 0 && threadIdx.x == 0) *out_loss = 0.f;
    const int r = blockIdx.x * 8 + (threadIdx.x >> 5);
    const size_t i0 = (size_t)r * D + (threadIdx.x & 31) * 8;
    float4 v0 = *(const float4*)(E + i0);
    float4 v1 = *(const float4*)(E + i0 + 4);
    float v[8] = {v0.x, v0.y, v0.z, v0.w, v1.x, v1.y, v1.z, v1.w};
    f16x8 h, l;
    float s = 0.f;
    #pragma unroll
    for (int j = 0; j < 8; ++j) {
        _Float16 hh = (_Float16)v[j];
        h[j] = hh;
        l[j] = (_Float16)(v[j] - (float)hh);
        s += v[j] * v[j];
    }
    *(f16x8*)(Eh + i0) = h;
    *(f16x8*)(El + i0) = l;
    #pragma unroll
    for (int off = 1; off < 32; off <<= 1) s += __shfl_xor(s, off, 64);
    if ((threadIdx.x & 31) == 0) enorm[r] = s;
}

// ---- main: pipelined split-f16 MFMA + argmin + gather + loss ----
__global__ __launch_bounds__(512, 2) void vq_mfma_kernel(
    const float* __restrict__ X,
    const _Float16* __restrict__ Eh, const _Float16* __restrict__ El,
    const float* __restrict__ enorm, const float* __restrict__ E,
    float* __restrict__ out_vals, float* __restrict__ out_idx,
    float* __restrict__ out_loss) {
    // A: fp32, 128B rows = 8 x 16B chunks, phys chunk = c ^ (r&7) (R5-verified).
    // B: f16 hi/lo, 64B rows = 4 x 16B slots, phys = (c + (r>>1)) & 3 (R5-verified).
    __shared__ __align__(16) float    Asf[2][BM * BK];   // 2 x 32 KB fp32 A
    __shared__ __align__(16) _Float16 Bsh[2][BN * BK];   // 2 x 16 KB
    __shared__ __align__(16) _Float16 Bsl[2][BN * BK];   // 2 x 16 KB
    __shared__ float s_en[KCB];                          // 4 KB
    __shared__ float s_bd[BM];                           // 1 KB
    __shared__ int   s_bi[BM];                           // 1 KB
    __shared__ float s_red[8];

    const int tid  = threadIdx.x;
    const int w    = tid >> 6;        // wave 0..7
    const int lane = tid & 63;
    const int quad = lane >> 4;
    const int l16  = lane & 15;
    const int wm   = w >> 1;          // wave row group (0..3) -> rows wm*64..+63
    const int wn   = w & 1;           // wave col group (0..1) -> cols wn*128..+127
    const int sxa  = l16 & 7;         // A frag-read row swizzle (r&7 == l16&7)
    const int row0 = blockIdx.x * BM;

    // A staging: 32 chunks of 1KB (8 fp32 rows each); wave w owns chunks w*4..+3.
    const int sa_row = lane >> 3;
    const int sa_off = ((lane & 7) ^ sa_row) * 4;             // float offset in 32-k row
    // B staging: 16 chunks of 1KB (16 f16 rows each); wave w owns chunks w*2, w*2+1.
    const int sb_row = lane >> 2;
    const int sb_off = ((((lane & 3) - (lane >> 3)) & 3) << 3);   // f16 offset
    // B frag-read physical slot (col bases are multiples of 16 -> r&15 == l16)
    const int kob = ((quad + ((l16 >> 1) & 3)) & 3) << 3;

    // s_en fill
    s_en[tid]       = enorm[tid];
    s_en[tid + 512] = enorm[tid + 512];

    auto STAGE = [&](int buf, int s) {
        const int kb   = (s & 7) * BK;
        const int col0 = (s >> 3) * BN;
        #pragma unroll
        for (int t = 0; t < 4; ++t) {
            const int chunk = w * 4 + t;                 // 0..31 (8 fp32 rows each)
            const int gr = row0 + chunk * 8 + sa_row;
            GLOAD_LDS16(X + (size_t)gr * D + kb + sa_off, &Asf[buf][chunk * 256]);
        }
        #pragma unroll
        for (int t = 0; t < 2; ++t) {
            const int chunk = w * 2 + t;                 // 0..15 (16 f16 rows each)
            const int gr = col0 + chunk * 16 + sb_row;
            const size_t gb = (size_t)gr * D + kb + sb_off;
            GLOAD_LDS16(Eh + gb, &Bsh[buf][chunk * 512]);
            GLOAD_LDS16(El + gb, &Bsl[buf][chunk * 512]);
        }
    };  // 8 loads per thread per call

    float rb_d[4][4];
    int   rb_i[4][4];
    #pragma unroll
    for (int i = 0; i < 4; ++i)
        #pragma unroll
        for (int r = 0; r < 4; ++r) { rb_d[i][r] = 3.4e38f; rb_i[i][r] = 0; }
    float xs = 0.f;               // sum of x^2 (each element once: nt==0, wn==0)
    f32x4 acc[4][8];

    STAGE(0, 0);
    asm volatile("s_waitcnt lgkmcnt(0)" ::: "memory");   // s_en writes done

    #pragma unroll 2
    for (int s = 0; s < NSTEP; ++s) {
        const int cur = s & 1;
        if (s + 1 < NSTEP) {
            STAGE(cur ^ 1, s + 1);                       // 8 loads in flight
            asm volatile("s_waitcnt vmcnt(8)" ::: "memory");  // prev step's 8 landed
        } else {
            asm volatile("s_waitcnt vmcnt(0)" ::: "memory");
        }
        __builtin_amdgcn_s_barrier();                    // cur valid block-wide

        if ((s & 7) == 0) {
            #pragma unroll
            for (int i = 0; i < 4; ++i)
                #pragma unroll
                for (int j = 0; j < 8; ++j) acc[i][j] = (f32x4)0.0f;
        }

        const float*    As = Asf[cur];
        const _Float16* Bh = Bsh[cur];
        const _Float16* Bl = Bsl[cur];

        // A frags: read fp32, split to f16 hi/lo in-register (R5-verified path)
        f16x8 ah[4], al[4];
        #pragma unroll
        for (int i = 0; i < 4; ++i) {
            const float* rp = As + (wm * 64 + i * 16 + l16) * BK;
            const f32x4 v0 = *(const f32x4*)(rp + ((((quad << 1))     ^ sxa) << 2));
            const f32x4 v1 = *(const f32x4*)(rp + ((((quad << 1) | 1) ^ sxa) << 2));
            const float f[8] = {v0.x, v0.y, v0.z, v0.w, v1.x, v1.y, v1.z, v1.w};
            #pragma unroll
            for (int e = 0; e < 8; ++e) {
                const _Float16 hh = (_Float16)f[e];
                ah[i][e] = hh;
                al[i][e] = (_Float16)(f[e] - (float)hh);
            }
            if (wn == 0 && s < 8) {
                #pragma unroll
                for (int e = 0; e < 8; ++e) xs += f[e] * f[e];
            }
        }

        __builtin_amdgcn_s_setprio(1);
        #pragma unroll
        for (int j = 0; j < 8; ++j) {
            const int n = (wn * 128 + j * 16 + l16) * BK + kob;
            const f16x8 bh = *(const f16x8*)&Bh[n];
            const f16x8 bl = *(const f16x8*)&Bl[n];
            #pragma unroll
            for (int i = 0; i < 4; ++i) {
                acc[i][j] = __builtin_amdgcn_mfma_f32_16x16x32_f16(ah[i], bh, acc[i][j], 0, 0, 0);
                acc[i][j] = __builtin_amdgcn_mfma_f32_16x16x32_f16(al[i], bh, acc[i][j], 0, 0, 0);
                acc[i][j] = __builtin_amdgcn_mfma_f32_16x16x32_f16(ah[i], bl, acc[i][j], 0, 0, 0);
            }
        }
        __builtin_amdgcn_s_setprio(0);

        if ((s & 7) == 7) {                 // nt complete: fold argmin
            const int nt = s >> 3;
            #pragma unroll
            for (int j = 0; j < 8; ++j) {
                const int c = nt * BN + wn * 128 + j * 16 + l16;
                const float en = s_en[c];
                #pragma unroll
                for (int i = 0; i < 4; ++i)
                    #pragma unroll
                    for (int r = 0; r < 4; ++r) {
                        const float sd = en - 2.0f * acc[i][j][r];
                        if (sd < rb_d[i][r]) { rb_d[i][r] = sd; rb_i[i][r] = c; }
                    }
            }
        }
        __builtin_amdgcn_s_barrier();       // all waves done reading cur
    }

    // fold the 16 lanes of each quad (they partition this wave's col slice)
    #pragma unroll
    for (int off = 1; off < 16; off <<= 1) {
        #pragma unroll
        for (int i = 0; i < 4; ++i)
            #pragma unroll
            for (int r = 0; r < 4; ++r) {
                const float od = __shfl_xor(rb_d[i][r], off, 64);
                const int   oi = __shfl_xor(rb_i[i][r], off, 64);
                if (od < rb_d[i][r] || (od == rb_d[i][r] && oi < rb_i[i][r])) {
                    rb_d[i][r] = od; rb_i[i][r] = oi;
                }
            }
    }
    // two-phase deterministic merge of the wn=0 / wn=1 halves
    if (wn == 0 && l16 == 0) {
        #pragma unroll
        for (int i = 0; i < 4; ++i)
            #pragma unroll
            for (int r = 0; r < 4; ++r) {
                const int m = wm * 64 + i * 16 + quad * 4 + r;
                s_bd[m] = rb_d[i][r]; s_bi[m] = rb_i[i][r];
            }
    }
    __syncthreads();
    if (wn == 1 && l16 == 0) {
        #pragma unroll
        for (int i = 0; i < 4; ++i)
            #pragma unroll
            for (int r = 0; r < 4; ++r) {
                const int m = wm * 64 + i * 16 + quad * 4 + r;
                if (rb_d[i][r] < s_bd[m] || (rb_d[i][r] == s_bd[m] && rb_i[i][r] < s_bi[m])) {
                    s_bd[m] = rb_d[i][r]; s_bi[m] = rb_i[i][r];
                }
            }
    }
    __syncthreads();

    // epilogue: indexes + loss partial (sum|x|^2 + min dist), then gather
    float part = xs;
    if (tid < BM) {
        out_idx[row0 + tid] = (float)s_bi[tid];
        part += s_bd[tid];
    }

    const int col = tid & 255;
    const int sub = tid >> 8;
    #pragma unroll 4
    for (int it = 0; it < BM / 2; ++it) {
        const int r  = it * 2 + sub;
        const int bi = s_bi[r];
        out_vals[(size_t)(row0 + r) * D + col] = E[(size_t)bi * D + col];
    }

    #pragma unroll
    for (int off = 1; off < 64; off <<= 1) part += __shfl_xor(part, off, 64);
    if (lane == 0) s_red[w] = part;
    __syncthreads();
    if (tid == 0) {
        float tot = 0.f;
        #pragma unroll
        for (int i = 0; i < 8; ++i) tot += s_red[i];
        atomicAdd(out_loss, tot * (1.1f / 16777216.f));  // loss1 + 0.1*loss2
    }
}

extern "C" void kernel_launch(void* const* d_in, const int* in_sizes, int n_in,
                              void* d_out, int out_size, void* d_ws, size_t ws_size,
                              hipStream_t stream) {
    const float* X = (const float*)d_in[0];
    const float* E = (const float*)d_in[1];
    float* out      = (float*)d_out;
    float* out_vals = out;
    float* out_idx  = out + (size_t)BT * D;
    float* out_loss = out + (size_t)BT * D + BT;

    char* ws = (char*)d_ws;
    _Float16* Eh    = (_Float16*)ws;
    _Float16* El    = Eh + (size_t)KCB * D;
    float*    enorm = (float*)(El + (size_t)KCB * D);
    (void)ws_size; (void)n_in; (void)in_sizes; (void)out_size;

    split_e_kernel<<<KCB / 8, 256, 0, stream>>>(E, Eh, El, enorm, out_loss);
    vq_mfma_kernel<<<BT / BM, 512, 0, stream>>>(X, Eh, El, enorm, E,
                                                out_vals, out_idx, out_loss);
}

// Round 7
// 193.816 us; speedup vs baseline: 2.0175x; 1.0901x over previous
//
#include <hip/hip_runtime.h>
#include <stdint.h>

// VQ-VAE quantize forward, MI355X. Split-f16 MFMA distance GEMM.
// R12: A persists in REGISTERS. Wave tile 32 rows x 128 cols (8 waves,
// BM=256, BN=128/step). Prologue: 4 passes stage X through a 64KB LDS
// scratch (R11-verified XOR-chunk swizzle), each wave splits its 32 rows
// x 256 K into persistent hi/lo f16 frags (128 VGPR) ONCE. Main loop per
// step: 2 B gload_lds (vmcnt(2)) + 16 B ds_reads + 48 MFMA — no A LDS
// reads, no in-loop split. Each wave covers all cols of its rows -> no
// cross-wave argmin merge. Counted vmcnt, raw s_barrier, setprio (T5).
// Distances bit-identical to R5..R11 (same split math, same hh/lh/hl
// order, same kc-ascending chain, same tie-breaks) -> same argmin/absmax.
// out = [values (BT*D)] [indexes as float (BT)] [loss (1)]

#define BT    65536     // 16*4096 rows
#define D     256       // codeword size
#define KCB   1024      // codebook size
#define BM    256       // rows per block tile
#define BN    128       // cols per step
#define NTT   (KCB/BN)  // 8 col tiles
#define BK    32        // k chunk

typedef float    f32x4 __attribute__((ext_vector_type(4)));
typedef _Float16 f16x8 __attribute__((ext_vector_type(8)));

#define GLOAD_LDS16(g, l) \
  __builtin_amdgcn_global_load_lds((const __attribute__((address_space(1))) void*)(g), \
                                   (__attribute__((address_space(3))) void*)(l), 16, 0, 0)

// ---- split E -> Eh, El + fp32 |e|^2; also zeroes out_loss (1MB in; ~3us) ----
__global__ __launch_bounds__(256) void split_e_kernel(const float* __restrict__ E,
                                                      _Float16* __restrict__ Eh,
                                                      _Float16* __restrict__ El,
                                                      float* __restrict__ enorm,
                                                      float* __restrict__ out_loss) {
    if (blockIdx.x == 0 && threadIdx.x == 0) *out_loss = 0.f;
    const int r = blockIdx.x * 8 + (threadIdx.x >> 5);
    const size_t i0 = (size_t)r * D + (threadIdx.x & 31) * 8;
    float4 v0 = *(const float4*)(E + i0);
    float4 v1 = *(const float4*)(E + i0 + 4);
    float v[8] = {v0.x, v0.y, v0.z, v0.w, v1.x, v1.y, v1.z, v1.w};
    f16x8 h, l;
    float s = 0.f;
    #pragma unroll
    for (int j = 0; j < 8; ++j) {
        _Float16 hh = (_Float16)v[j];
        h[j] = hh;
        l[j] = (_Float16)(v[j] - (float)hh);
        s += v[j] * v[j];
    }
    *(f16x8*)(Eh + i0) = h;
    *(f16x8*)(El + i0) = l;
    #pragma unroll
    for (int off = 1; off < 32; off <<= 1) s += __shfl_xor(s, off, 64);
    if ((threadIdx.x & 31) == 0) enorm[r] = s;
}

// ---- main: A-in-register pipelined split-f16 MFMA + argmin + gather + loss
__global__ __launch_bounds__(512, 2) void vq_mfma_kernel(
    const float* __restrict__ X,
    const _Float16* __restrict__ Eh, const _Float16* __restrict__ El,
    const float* __restrict__ enorm, const float* __restrict__ E,
    float* __restrict__ out_vals, float* __restrict__ out_idx,
    float* __restrict__ out_loss) {
    // X scratch: 64 rows x 256 f32 (1KB rows = 64 16B chunks); phys chunk
    // p = c ^ (r&7) (R11-verified family; frag reads 2-way aliased = free).
    // B: f16 hi/lo, 64B rows = 4 x 16B slots, phys = (c + (r>>1)) & 3
    // (R5/R8-verified: 0 conflicts).
    __shared__ __align__(16) float    Xs[64 * D];        // 64 KB (prologue only)
    __shared__ __align__(16) _Float16 Bsh[2][BN * BK];   // 2 x 8 KB
    __shared__ __align__(16) _Float16 Bsl[2][BN * BK];   // 2 x 8 KB
    __shared__ float s_en[KCB];                          // 4 KB
    __shared__ float s_bd[BM];                           // 1 KB
    __shared__ int   s_bi[BM];                           // 1 KB
    __shared__ float s_red[8];

    const int tid  = threadIdx.x;
    const int w    = tid >> 6;        // wave 0..7 -> rows w*32..w*32+31
    const int lane = tid & 63;
    const int quad = lane >> 4;
    const int l16  = lane & 15;
    const int sxa  = l16 & 7;
    const int row0 = blockIdx.x * BM;

    // B staging lane constants (R11 verbatim; linear LDS dest, swizzle folded
    // into the per-lane GLOBAL source address)
    const int sb_row = lane >> 2;                                 // row in 16-row chunk
    const int sb_off = ((((lane & 3) - (lane >> 3)) & 3) << 3);   // f16 offset
    // B frag-read physical slot (row bases are multiples of 16)
    const int kob = ((quad + ((l16 >> 1) & 3)) & 3) << 3;

    auto STAGE_B = [&](int buf, int col0, int kb) {
        const int gr = col0 + w * 16 + sb_row;        // wave w stages chunk w
        const size_t gb = (size_t)gr * D + kb + sb_off;
        GLOAD_LDS16(Eh + gb, &Bsh[buf][w * 512]);
        GLOAD_LDS16(El + gb, &Bsl[buf][w * 512]);
    };  // 2 loads per thread per call

    // s_en fill
    s_en[tid]       = enorm[tid];
    s_en[tid + 512] = enorm[tid + 512];

    STAGE_B(0, 0, 0);                 // lands during prologue drains

    // ---- prologue: persist this wave's A slice (32 rows x 256 K) in regs ----
    f16x8 pah[2][8], pal[2][8];       // 128 VGPR
    float xs = 0.f;                   // sum of x^2 (each element exactly once)
    for (int p = 0; p < 4; ++p) {
        #pragma unroll
        for (int rr = 0; rr < 8; ++rr) {
            const int sr = w * 8 + rr;                // scratch row 0..63
            const int gr = row0 + p * 64 + sr;
            GLOAD_LDS16(X + (size_t)gr * D + ((lane ^ rr) << 2), &Xs[sr * D]);
        }
        asm volatile("s_waitcnt vmcnt(0) lgkmcnt(0)" ::: "memory");
        __builtin_amdgcn_s_barrier();
        if ((w >> 1) == p) {                          // waves 2p, 2p+1 consume
            const int srb = (w & 1) * 32;
            #pragma unroll
            for (int i = 0; i < 2; ++i) {
                const float* rp = &Xs[(srb + i * 16 + l16) * D];
                #pragma unroll
                for (int kc = 0; kc < 8; ++kc) {
                    const int c0 = kc * 8 + quad * 2;
                    const f32x4 v0 = *(const f32x4*)(rp + (((c0)     ^ sxa) << 2));
                    const f32x4 v1 = *(const f32x4*)(rp + (((c0 | 1) ^ sxa) << 2));
                    const float f[8] = {v0.x, v0.y, v0.z, v0.w, v1.x, v1.y, v1.z, v1.w};
                    #pragma unroll
                    for (int e = 0; e < 8; ++e) {
                        const _Float16 hh = (_Float16)f[e];
                        pah[i][kc][e] = hh;
                        pal[i][kc][e] = (_Float16)(f[e] - (float)hh);
                        xs += f[e] * f[e];
                    }
                }
            }
        }
        __builtin_amdgcn_s_barrier();
    }

    float rb_d[2][4];
    int   rb_i[2][4];
    #pragma unroll
    for (int i = 0; i < 2; ++i)
        #pragma unroll
        for (int r = 0; r < 4; ++r) { rb_d[i][r] = 3.4e38f; rb_i[i][r] = 0; }
    f32x4 acc[2][8];

    // ---- main loop: 8 nt x 8 kc steps; kc fully unrolled (compile-time
    // pah/pal index per rule #20; buffer parity cur = kc&1 compile-time) ----
    for (int nt = 0; nt < NTT; ++nt) {
        const int col0 = nt * BN;
        #pragma unroll
        for (int kc = 0; kc < 8; ++kc) {
            const int cur = kc & 1;
            if (kc < 7) {
                STAGE_B(cur ^ 1, col0, (kc + 1) * BK);
                asm volatile("s_waitcnt vmcnt(2)" ::: "memory");
            } else if (nt < NTT - 1) {
                STAGE_B(cur ^ 1, col0 + BN, 0);
                asm volatile("s_waitcnt vmcnt(2)" ::: "memory");
            } else {
                asm volatile("s_waitcnt vmcnt(0)" ::: "memory");
            }
            __builtin_amdgcn_s_barrier();             // cur landed block-wide

            if (kc == 0) {
                #pragma unroll
                for (int i = 0; i < 2; ++i)
                    #pragma unroll
                    for (int j = 0; j < 8; ++j) acc[i][j] = (f32x4)0.0f;
            }

            const _Float16* Bh = Bsh[cur];
            const _Float16* Bl = Bsl[cur];

            __builtin_amdgcn_s_setprio(1);
            #pragma unroll
            for (int j = 0; j < 8; ++j) {
                const int n = (j * 16 + l16) * BK + kob;
                const f16x8 bh = *(const f16x8*)&Bh[n];
                const f16x8 bl = *(const f16x8*)&Bl[n];
                #pragma unroll
                for (int i = 0; i < 2; ++i) {
                    acc[i][j] = __builtin_amdgcn_mfma_f32_16x16x32_f16(pah[i][kc], bh, acc[i][j], 0, 0, 0);
                    acc[i][j] = __builtin_amdgcn_mfma_f32_16x16x32_f16(pal[i][kc], bh, acc[i][j], 0, 0, 0);
                    acc[i][j] = __builtin_amdgcn_mfma_f32_16x16x32_f16(pah[i][kc], bl, acc[i][j], 0, 0, 0);
                }
            }
            __builtin_amdgcn_s_setprio(0);

            if (kc == 7) {                 // nt complete: fold argmin
                #pragma unroll
                for (int j = 0; j < 8; ++j) {
                    const int c = col0 + j * 16 + l16;
                    const float en = s_en[c];
                    #pragma unroll
                    for (int i = 0; i < 2; ++i)
                        #pragma unroll
                        for (int r = 0; r < 4; ++r) {
                            const float sd = en - 2.0f * acc[i][j][r];
                            if (sd < rb_d[i][r]) { rb_d[i][r] = sd; rb_i[i][r] = c; }
                        }
                }
            }
            __builtin_amdgcn_s_barrier();  // all waves done reading cur
        }
    }

    // fold the 16 lanes of each quad (they partition this wave's cols);
    // each wave owns distinct rows -> no cross-wave merge needed
    #pragma unroll
    for (int off = 1; off < 16; off <<= 1) {
        #pragma unroll
        for (int i = 0; i < 2; ++i)
            #pragma unroll
            for (int r = 0; r < 4; ++r) {
                const float od = __shfl_xor(rb_d[i][r], off, 64);
                const int   oi = __shfl_xor(rb_i[i][r], off, 64);
                if (od < rb_d[i][r] || (od == rb_d[i][r] && oi < rb_i[i][r])) {
                    rb_d[i][r] = od; rb_i[i][r] = oi;
                }
            }
    }
    if (l16 == 0) {
        #pragma unroll
        for (int i = 0; i < 2; ++i)
            #pragma unroll
            for (int r = 0; r < 4; ++r) {
                const int m = w * 32 + i * 16 + quad * 4 + r;    // 0..255
                s_bd[m] = rb_d[i][r]; s_bi[m] = rb_i[i][r];
            }
    }
    __syncthreads();

    // epilogue: indexes + loss partial (sum|x|^2 + min dist), then gather
    float part = xs;
    if (tid < BM) {
        out_idx[row0 + tid] = (float)s_bi[tid];
        part += s_bd[tid];
    }

    const int col = tid & 255;
    const int sub = tid >> 8;
    #pragma unroll 4
    for (int it = 0; it < BM / 2; ++it) {
        const int r  = it * 2 + sub;
        const int bi = s_bi[r];
        out_vals[(size_t)(row0 + r) * D + col] = E[(size_t)bi * D + col];
    }

    #pragma unroll
    for (int off = 1; off < 64; off <<= 1) part += __shfl_xor(part, off, 64);
    if (lane == 0) s_red[w] = part;
    __syncthreads();
    if (tid == 0) {
        float tot = 0.f;
        #pragma unroll
        for (int i = 0; i < 8; ++i) tot += s_red[i];
        atomicAdd(out_loss, tot * (1.1f / 16777216.f));  // loss1 + 0.1*loss2
    }
}

extern "C" void kernel_launch(void* const* d_in, const int* in_sizes, int n_in,
                              void* d_out, int out_size, void* d_ws, size_t ws_size,
                              hipStream_t stream) {
    const float* X = (const float*)d_in[0];
    const float* E = (const float*)d_in[1];
    float* out      = (float*)d_out;
    float* out_vals = out;
    float* out_idx  = out + (size_t)BT * D;
    float* out_loss = out + (size_t)BT * D + BT;

    char* ws = (char*)d_ws;
    _Float16* Eh    = (_Float16*)ws;
    _Float16* El    = Eh + (size_t)KCB * D;
    float*    enorm = (float*)(El + (size_t)KCB * D);
    (void)ws_size; (void)n_in; (void)in_sizes; (void)out_size;

    split_e_kernel<<<KCB / 8, 256, 0, stream>>>(E, Eh, El, enorm, out_loss);
    vq_mfma_kernel<<<BT / BM, 512, 0, stream>>>(X, Eh, El, enorm, E,
                                                out_vals, out_idx, out_loss);
}

// Round 8
// 189.904 us; speedup vs baseline: 2.0591x; 1.0206x over previous
//
#include <hip/hip_runtime.h>
#include <stdint.h>

// VQ-VAE quantize forward, MI355X. Split-f16 MFMA distance GEMM.
// R13 = R12 (A persistent in registers: wave = 32 rows x 128 cols, split
// once in prologue, no in-loop A reads/split) with DOUBLE-K phases:
// each phase stages K=64 of B (4 gload_lds, vmcnt(4)) and runs 96 MFMA
// between one barrier pair -> 32 phases instead of 64 steps; per-barrier
// overhead per MFMA halves. B buffers (2 dbuf x 2 half x hi/lo = 64KB)
// overlay the 64KB prologue X-scratch (prologue-only; barrier-separated).
// nt/q/sub loop keeps pah[i][kc] compile-time (rule #20). Distances
// bit-identical to R5..R12 (same split math, same hh/lh/hl order, same
// kc-ascending chain, same tie-breaks) -> same argmin/absmax.
// out = [values (BT*D)] [indexes as float (BT)] [loss (1)]

#define BT    65536     // 16*4096 rows
#define D     256       // codeword size
#define KCB   1024      // codebook size
#define BM    256       // rows per block tile
#define BN    128       // cols per phase
#define BK    32        // k sub-chunk (MFMA granularity kept at 32)

typedef float    f32x4 __attribute__((ext_vector_type(4)));
typedef _Float16 f16x8 __attribute__((ext_vector_type(8)));

#define GLOAD_LDS16(g, l) \
  __builtin_amdgcn_global_load_lds((const __attribute__((address_space(1))) void*)(g), \
                                   (__attribute__((address_space(3))) void*)(l), 16, 0, 0)

// ---- split E -> Eh, El + fp32 |e|^2; also zeroes out_loss (1MB in; ~3us) ----
__global__ __launch_bounds__(256) void split_e_kernel(const float* __restrict__ E,
                                                      _Float16* __restrict__ Eh,
                                                      _Float16* __restrict__ El,
                                                      float* __restrict__ enorm,
                                                      float* __restrict__ out_loss) {
    if (blockIdx.x == 0 && threadIdx.x == 0) *out_loss = 0.f;
    const int r = blockIdx.x * 8 + (threadIdx.x >> 5);
    const size_t i0 = (size_t)r * D + (threadIdx.x & 31) * 8;
    float4 v0 = *(const float4*)(E + i0);
    float4 v1 = *(const float4*)(E + i0 + 4);
    float v[8] = {v0.x, v0.y, v0.z, v0.w, v1.x, v1.y, v1.z, v1.w};
    f16x8 h, l;
    float s = 0.f;
    #pragma unroll
    for (int j = 0; j < 8; ++j) {
        _Float16 hh = (_Float16)v[j];
        h[j] = hh;
        l[j] = (_Float16)(v[j] - (float)hh);
        s += v[j] * v[j];
    }
    *(f16x8*)(Eh + i0) = h;
    *(f16x8*)(El + i0) = l;
    #pragma unroll
    for (int off = 1; off < 32; off <<= 1) s += __shfl_xor(s, off, 64);
    if ((threadIdx.x & 31) == 0) enorm[r] = s;
}

// ---- main: A-in-register, double-K phases, split-f16 MFMA + argmin + loss
__global__ __launch_bounds__(512, 2) void vq_mfma_kernel(
    const float* __restrict__ X,
    const _Float16* __restrict__ Eh, const _Float16* __restrict__ El,
    const float* __restrict__ enorm, const float* __restrict__ E,
    float* __restrict__ out_vals, float* __restrict__ out_idx,
    float* __restrict__ out_loss) {
    // Bmem overlay: prologue = X scratch (64 rows x 256 f32, 1KB rows of
    // 64 16B chunks, phys chunk = c ^ (r&7), R11/R12-verified).
    // main loop = B buffers [buf][half][hl][BN*BK] f16 (64B rows, 4 slots,
    // phys slot = (c + (r>>1)) & 3, R5/R8-verified: 0 conflicts).
    __shared__ __align__(16) char Bmem[8 * BN * BK * 2];   // 64 KB
    __shared__ float s_en[KCB];                            // 4 KB
    __shared__ float s_bd[BM];                             // 1 KB
    __shared__ int   s_bi[BM];                             // 1 KB
    __shared__ float s_red[8];

    float*    const Xs = (float*)Bmem;
    _Float16* const BB = (_Float16*)Bmem;

    const int tid  = threadIdx.x;
    const int w    = tid >> 6;        // wave 0..7 -> rows w*32..w*32+31
    const int lane = tid & 63;
    const int quad = lane >> 4;
    const int l16  = lane & 15;
    const int sxa  = l16 & 7;
    const int row0 = blockIdx.x * BM;

    // B staging lane constants (R11/R12 verbatim; linear LDS dest, swizzle
    // folded into the per-lane GLOBAL source address)
    const int sb_row = lane >> 2;                                 // row in 16-row chunk
    const int sb_off = ((((lane & 3) - (lane >> 3)) & 3) << 3);   // f16 offset
    // B frag-read physical slot (row bases are multiples of 16)
    const int kob = ((quad + ((l16 >> 1) & 3)) & 3) << 3;

    auto STAGE_PH = [&](int buf, int step) {   // step = nt*4 + q of TARGET phase
        const int col0 = (step >> 2) * BN;
        const int kb0  = (step & 3) * (2 * BK);
        #pragma unroll
        for (int h = 0; h < 2; ++h) {
            const int gr = col0 + w * 16 + sb_row;     // wave w stages chunk w
            const size_t gb = (size_t)gr * D + kb0 + h * BK + sb_off;
            GLOAD_LDS16(Eh + gb, BB + (buf * 4 + h * 2 + 0) * (BN * BK) + w * 512);
            GLOAD_LDS16(El + gb, BB + (buf * 4 + h * 2 + 1) * (BN * BK) + w * 512);
        }
    };  // 4 loads per thread per call

    // s_en fill
    s_en[tid]       = enorm[tid];
    s_en[tid + 512] = enorm[tid + 512];

    // ---- prologue: persist this wave's A slice (32 rows x 256 K) in regs ----
    f16x8 pah[2][8], pal[2][8];       // 128 VGPR
    float xs = 0.f;                   // sum of x^2 (each element exactly once)
    for (int p = 0; p < 4; ++p) {
        #pragma unroll
        for (int rr = 0; rr < 8; ++rr) {
            const int sr = w * 8 + rr;                // scratch row 0..63
            const int gr = row0 + p * 64 + sr;
            GLOAD_LDS16(X + (size_t)gr * D + ((lane ^ rr) << 2), &Xs[sr * D]);
        }
        asm volatile("s_waitcnt vmcnt(0) lgkmcnt(0)" ::: "memory");
        __builtin_amdgcn_s_barrier();
        if ((w >> 1) == p) {                          // waves 2p, 2p+1 consume
            const int srb = (w & 1) * 32;
            #pragma unroll
            for (int i = 0; i < 2; ++i) {
                const float* rp = &Xs[(srb + i * 16 + l16) * D];
                #pragma unroll
                for (int kc = 0; kc < 8; ++kc) {
                    const int c0 = kc * 8 + quad * 2;
                    const f32x4 v0 = *(const f32x4*)(rp + (((c0)     ^ sxa) << 2));
                    const f32x4 v1 = *(const f32x4*)(rp + (((c0 | 1) ^ sxa) << 2));
                    const float f[8] = {v0.x, v0.y, v0.z, v0.w, v1.x, v1.y, v1.z, v1.w};
                    #pragma unroll
                    for (int e = 0; e < 8; ++e) {
                        const _Float16 hh = (_Float16)f[e];
                        pah[i][kc][e] = hh;
                        pal[i][kc][e] = (_Float16)(f[e] - (float)hh);
                        xs += f[e] * f[e];
                    }
                }
            }
        }
        __builtin_amdgcn_s_barrier();   // Xs reads done; safe to overlay with B
    }

    float rb_d[2][4];
    int   rb_i[2][4];
    #pragma unroll
    for (int i = 0; i < 2; ++i)
        #pragma unroll
        for (int r = 0; r < 4; ++r) { rb_d[i][r] = 3.4e38f; rb_i[i][r] = 0; }
    f32x4 acc[2][8];

    // ---- main loop: 8 nt x 4 phases; phase = K=64 (2 kc sub-steps).
    // q, sub unrolled -> pah index & buffer parity compile-time (rule #20).
    STAGE_PH(0, 0);
    for (int nt = 0; nt < 8; ++nt) {
        const int col0 = nt * BN;
        #pragma unroll
        for (int q = 0; q < 4; ++q) {
            const int cur = q & 1;
            if (nt == 7 && q == 3) {
                asm volatile("s_waitcnt vmcnt(0)" ::: "memory");
            } else {
                STAGE_PH(cur ^ 1, nt * 4 + q + 1);    // 4 loads in flight
                asm volatile("s_waitcnt vmcnt(4)" ::: "memory");  // prev phase landed
            }
            __builtin_amdgcn_s_barrier();             // cur valid block-wide

            if (q == 0) {
                #pragma unroll
                for (int i = 0; i < 2; ++i)
                    #pragma unroll
                    for (int j = 0; j < 8; ++j) acc[i][j] = (f32x4)0.0f;
            }

            #pragma unroll
            for (int sub = 0; sub < 2; ++sub) {
                const int kc = q * 2 + sub;           // compile-time
                const _Float16* Bh = BB + (cur * 4 + sub * 2 + 0) * (BN * BK);
                const _Float16* Bl = BB + (cur * 4 + sub * 2 + 1) * (BN * BK);
                __builtin_amdgcn_s_setprio(1);
                #pragma unroll
                for (int j = 0; j < 8; ++j) {
                    const int n = (j * 16 + l16) * BK + kob;
                    const f16x8 bh = *(const f16x8*)&Bh[n];
                    const f16x8 bl = *(const f16x8*)&Bl[n];
                    #pragma unroll
                    for (int i = 0; i < 2; ++i) {
                        acc[i][j] = __builtin_amdgcn_mfma_f32_16x16x32_f16(pah[i][kc], bh, acc[i][j], 0, 0, 0);
                        acc[i][j] = __builtin_amdgcn_mfma_f32_16x16x32_f16(pal[i][kc], bh, acc[i][j], 0, 0, 0);
                        acc[i][j] = __builtin_amdgcn_mfma_f32_16x16x32_f16(pah[i][kc], bl, acc[i][j], 0, 0, 0);
                    }
                }
                __builtin_amdgcn_s_setprio(0);
            }

            if (q == 3) {                 // nt complete: fold argmin
                #pragma unroll
                for (int j = 0; j < 8; ++j) {
                    const int c = col0 + j * 16 + l16;
                    const float en = s_en[c];
                    #pragma unroll
                    for (int i = 0; i < 2; ++i)
                        #pragma unroll
                        for (int r = 0; r < 4; ++r) {
                            const float sd = en - 2.0f * acc[i][j][r];
                            if (sd < rb_d[i][r]) { rb_d[i][r] = sd; rb_i[i][r] = c; }
                        }
                }
            }
            __builtin_amdgcn_s_barrier();  // all waves done reading cur
        }
    }

    // fold the 16 lanes of each quad (they partition this wave's cols);
    // each wave owns distinct rows -> no cross-wave merge needed
    #pragma unroll
    for (int off = 1; off < 16; off <<= 1) {
        #pragma unroll
        for (int i = 0; i < 2; ++i)
            #pragma unroll
            for (int r = 0; r < 4; ++r) {
                const float od = __shfl_xor(rb_d[i][r], off, 64);
                const int   oi = __shfl_xor(rb_i[i][r], off, 64);
                if (od < rb_d[i][r] || (od == rb_d[i][r] && oi < rb_i[i][r])) {
                    rb_d[i][r] = od; rb_i[i][r] = oi;
                }
            }
    }
    if (l16 == 0) {
        #pragma unroll
        for (int i = 0; i < 2; ++i)
            #pragma unroll
            for (int r = 0; r < 4; ++r) {
                const int m = w * 32 + i * 16 + quad * 4 + r;    // 0..255
                s_bd[m] = rb_d[i][r]; s_bi[m] = rb_i[i][r];
            }
    }
    __syncthreads();

    // epilogue: indexes + loss partial (sum|x|^2 + min dist), then gather
    float part = xs;
    if (tid < BM) {
        out_idx[row0 + tid] = (float)s_bi[tid];
        part += s_bd[tid];
    }

    const int col = tid & 255;
    const int sub = tid >> 8;
    #pragma unroll 4
    for (int it = 0; it < BM / 2; ++it) {
        const int r  = it * 2 + sub;
        const int bi = s_bi[r];
        out_vals[(size_t)(row0 + r) * D + col] = E[(size_t)bi * D + col];
    }

    #pragma unroll
    for (int off = 1; off < 64; off <<= 1) part += __shfl_xor(part, off, 64);
    if (lane == 0) s_red[w] = part;
    __syncthreads();
    if (tid == 0) {
        float tot = 0.f;
        #pragma unroll
        for (int i = 0; i < 8; ++i) tot += s_red[i];
        atomicAdd(out_loss, tot * (1.1f / 16777216.f));  // loss1 + 0.1*loss2
    }
}

extern "C" void kernel_launch(void* const* d_in, const int* in_sizes, int n_in,
                              void* d_out, int out_size, void* d_ws, size_t ws_size,
                              hipStream_t stream) {
    const float* X = (const float*)d_in[0];
    const float* E = (const float*)d_in[1];
    float* out      = (float*)d_out;
    float* out_vals = out;
    float* out_idx  = out + (size_t)BT * D;
    float* out_loss = out + (size_t)BT * D + BT;

    char* ws = (char*)d_ws;
    _Float16* Eh    = (_Float16*)ws;
    _Float16* El    = Eh + (size_t)KCB * D;
    float*    enorm = (float*)(El + (size_t)KCB * D);
    (void)ws_size; (void)n_in; (void)in_sizes; (void)out_size;

    split_e_kernel<<<KCB / 8, 256, 0, stream>>>(E, Eh, El, enorm, out_loss);
    vq_mfma_kernel<<<BT / BM, 512, 0, stream>>>(X, Eh, El, enorm, E,
                                                out_vals, out_idx, out_loss);
}